// Round 7
// baseline (625.858 us; speedup 1.0000x reference)
//
#include <hip/hip_runtime.h>
#include <hip/hip_cooperative_groups.h>

namespace cg = cooperative_groups;

#define N_NODES 20000
#define N_EDGES 320000
#define N_GRAPH 256
#define ECHUNK 2048
#define DCAP 64

__device__ __forceinline__ ushort f2b(float f) {  // fp32 -> bf16 RNE
  unsigned u = __float_as_uint(f);
  u += 0x7FFFu + ((u >> 16) & 1u);
  return (ushort)(u >> 16);
}
__device__ __forceinline__ float b2f(ushort u) {
  return __uint_as_float(((unsigned)u) << 16);
}

typedef __attribute__((ext_vector_type(8))) short bf16x8;
typedef __attribute__((ext_vector_type(4))) float f32x4;

// ---- bf16x8 accumulate helper (gather path) ----
__device__ __forceinline__ void acc8(float* a, uint4 u) {
  a[0] += __uint_as_float(u.x << 16);
  a[1] += __uint_as_float(u.x & 0xFFFF0000u);
  a[2] += __uint_as_float(u.y << 16);
  a[3] += __uint_as_float(u.y & 0xFFFF0000u);
  a[4] += __uint_as_float(u.z << 16);
  a[5] += __uint_as_float(u.z & 0xFFFF0000u);
  a[6] += __uint_as_float(u.w << 16);
  a[7] += __uint_as_float(u.w & 0xFFFF0000u);
}

// ---------------- FUSED agg + bf16 MFMA GEMM (layers 1 & 2) ----------------
// Gathers + sums dinv-prescaled neighbor rows of h (ld 80, 10 uint4 chunks)
// directly into the A-tile LDS (fp32 accum -> f2b), then the K=96 MFMA loop.
// Epilogue: bias + relu + dinv[row] prescale + bf16 store, zero cols [M,cwz).
template <int BN_T>  // BN = BN_T*16
__launch_bounds__(256)
__global__ void gemm_fused(const ushort* __restrict__ h,
                           const int* __restrict__ cnt,
                           const ushort* __restrict__ col_idx,
                           const float* __restrict__ dinv,
                           const ushort* __restrict__ Bt, int ldbt,
                           ushort* __restrict__ C, int ldc,
                           const float* __restrict__ bias,
                           int Nr, int M, int cwz) {
  constexpr int BM = 64, BN = BN_T * 16, LA = 104;
  __shared__ __align__(16) ushort Afull[BM][LA];
  __shared__ __align__(16) ushort Bsl[BN][40];
  const int tid = threadIdx.x;
  const int R = (Nr + BM - 1) / BM;
  const int RR = (R + 7) >> 3;
  const int xz = blockIdx.x & 7, g = blockIdx.x >> 3;
  const int by = xz * RR + g;
  if (by >= R) return;
  const int row0 = by * BM;
  const int lane = tid & 63, w = tid >> 6;
  const uint4* hv = (const uint4*)h;

  for (int task = tid; task < BM * 10; task += 256) {
    const int r = task / 10, c = task - r * 10;
    const int n = row0 + r;
    uint4 val = make_uint4(0u, 0u, 0u, 0u);
    if (n < Nr) {
      float a[8] = {};
      acc8(a, hv[(size_t)n * 10 + c]);  // self (prescaled)
      const int beg = n << 6;
      const int end = beg + min(cnt[n], DCAP);
      int e = beg;
      for (; e + 3 < end; e += 4) {
        int s0 = col_idx[e], s1 = col_idx[e + 1];
        int s2 = col_idx[e + 2], s3 = col_idx[e + 3];
        acc8(a, hv[(size_t)s0 * 10 + c]); acc8(a, hv[(size_t)s1 * 10 + c]);
        acc8(a, hv[(size_t)s2 * 10 + c]); acc8(a, hv[(size_t)s3 * 10 + c]);
      }
      for (; e < end; ++e) acc8(a, hv[(size_t)col_idx[e] * 10 + c]);
      const float dn = dinv[n];
      ushort o[8];
#pragma unroll
      for (int j = 0; j < 8; ++j) o[j] = f2b(dn * a[j]);
      val = *(uint4*)o;
    }
    *(uint4*)&Afull[r][c * 8] = val;
  }
  for (int task = tid; task < BM * 2; task += 256) {
    const int r = task >> 1, c2 = task & 1;
    *(uint4*)&Afull[r][80 + c2 * 8] = make_uint4(0u, 0u, 0u, 0u);
  }
  __syncthreads();

  f32x4 acc[BN_T] = {};
  const int mrow = w * 16;
  const int lm = lane & 15, lq = (lane >> 4) * 8;
  for (int t = 0; t < 3; ++t) {
    const int k0 = t * 32;
    for (int s = tid; s < BN * 4; s += 256) {
      const int br = s >> 2, bo = (s & 3) * 8;
      *(uint4*)&Bsl[br][bo] = *(const uint4*)&Bt[(size_t)br * ldbt + k0 + bo];
    }
    __syncthreads();
    bf16x8 af = *(const bf16x8*)&Afull[mrow + lm][k0 + lq];
#pragma unroll
    for (int nt = 0; nt < BN_T; ++nt) {
      bf16x8 bf = *(const bf16x8*)&Bsl[nt * 16 + lm][lq];
      acc[nt] = __builtin_amdgcn_mfma_f32_16x16x32_bf16(af, bf, acc[nt], 0, 0, 0);
    }
    __syncthreads();
  }

  const int rquad = (lane >> 4) * 4;
#pragma unroll
  for (int nt = 0; nt < BN_T; ++nt) {
    const int cc = nt * 16 + lm;
    if (cc >= cwz) continue;
    const bool cval = cc < M;
    const float bv = cval ? bias[cc] : 0.f;
#pragma unroll
    for (int r = 0; r < 4; ++r) {
      const int rr = row0 + mrow + rquad + r;
      if (rr >= Nr) continue;
      float v = cval ? fmaxf(acc[nt][r] + bv, 0.f) * dinv[rr] : 0.f;
      C[(size_t)rr * ldc + cc] = f2b(v);
    }
  }
}

// ---------------- FUSED agg + GEMM + segment-max pool (layer 3) ----------------
// h = xb16w (ld 160, 20 uint4 chunks, cols 156..159 zero). Full N=312 in one
// block (acc[20]); gather once; pool epilogue (<=2 graphs per 64-row tile).
__launch_bounds__(256)
__global__ void gemm_fused3(const ushort* __restrict__ h,
                            const int* __restrict__ cnt,
                            const ushort* __restrict__ col_idx,
                            const float* __restrict__ dinv,
                            const ushort* __restrict__ Bt, int ldbt,
                            int* __restrict__ pooled, int ldp,
                            const float* __restrict__ bias,
                            int Nr, int M,
                            const int* __restrict__ bA, const int* __restrict__ bB,
                            int nsplit, int gA, int gB, int gTot) {
  constexpr int BM = 64, BN = 320, LA = 168;
  __shared__ __align__(16) ushort Afull[BM][LA];   // 21504 B
  __shared__ __align__(16) ushort Bsl[BN][40];     // 25600 B
  __shared__ int Ps[2][BN];                        // 2560 B
  const int tid = threadIdx.x;
  const int R = (Nr + BM - 1) / BM;
  const int RR = (R + 7) >> 3;
  const int xz = blockIdx.x & 7, g = blockIdx.x >> 3;
  const int by = xz * RR + g;
  if (by >= R) return;
  const int row0 = by * BM;
  const int lane = tid & 63, w = tid >> 6;
  const uint4* hv = (const uint4*)h;

  // gather: 64 rows x 20 chunks (320 B/row, coalesced per row)
  for (int task = tid; task < BM * 20; task += 256) {
    const int r = task / 20, c = task - r * 20;
    const int n = row0 + r;
    uint4 val = make_uint4(0u, 0u, 0u, 0u);
    if (n < Nr) {
      float a[8] = {};
      acc8(a, hv[(size_t)n * 20 + c]);  // self (prescaled)
      const int beg = n << 6;
      const int end = beg + min(cnt[n], DCAP);
      int e = beg;
      for (; e + 3 < end; e += 4) {
        int s0 = col_idx[e], s1 = col_idx[e + 1];
        int s2 = col_idx[e + 2], s3 = col_idx[e + 3];
        acc8(a, hv[(size_t)s0 * 20 + c]); acc8(a, hv[(size_t)s1 * 20 + c]);
        acc8(a, hv[(size_t)s2 * 20 + c]); acc8(a, hv[(size_t)s3 * 20 + c]);
      }
      for (; e < end; ++e) acc8(a, hv[(size_t)col_idx[e] * 20 + c]);
      const float dn = dinv[n];
      ushort o[8];
#pragma unroll
      for (int j = 0; j < 8; ++j) o[j] = f2b(dn * a[j]);
      val = *(uint4*)o;
    }
    *(uint4*)&Afull[r][c * 8] = val;
  }
  for (int idx = tid; idx < 2 * BN; idx += 256) ((int*)Ps)[idx] = 0;
  __syncthreads();

  f32x4 acc[20] = {};
  const int mrow = w * 16;
  const int lm = lane & 15, lq = (lane >> 4) * 8;
  for (int t = 0; t < 5; ++t) {
    const int k0 = t * 32;
    for (int s = tid; s < BN * 4; s += 256) {
      const int br = s >> 2, bo = (s & 3) * 8;
      *(uint4*)&Bsl[br][bo] = *(const uint4*)&Bt[(size_t)br * ldbt + k0 + bo];
    }
    __syncthreads();
    bf16x8 af = *(const bf16x8*)&Afull[mrow + lm][k0 + lq];
#pragma unroll
    for (int nt = 0; nt < 20; ++nt) {
      bf16x8 bf = *(const bf16x8*)&Bsl[nt * 16 + lm][lq];
      acc[nt] = __builtin_amdgcn_mfma_f32_16x16x32_bf16(af, bf, acc[nt], 0, 0, 0);
    }
    __syncthreads();
  }

  // pool epilogue: local LDS atomicMax then one global atomicMax per (g,c)
  const int rquad = (lane >> 4) * 4;
  const int g0 = (row0 < nsplit) ? gA + bA[row0] : gB + bB[row0 - nsplit];
  int gr[4];
#pragma unroll
  for (int r = 0; r < 4; ++r) {
    const int rr = row0 + mrow + rquad + r;
    gr[r] = (rr < Nr) ? ((rr < nsplit) ? gA + bA[rr] : gB + bB[rr - nsplit]) - g0 : -1;
  }
#pragma unroll
  for (int nt = 0; nt < 20; ++nt) {
    const int cc = nt * 16 + lm;
    if (cc >= M) continue;
    const float bv = bias[cc];
#pragma unroll
    for (int r = 0; r < 4; ++r) {
      if (gr[r] < 0) continue;
      const float v = fmaxf(acc[nt][r] + bv, 0.f);
      atomicMax(&Ps[gr[r]][cc], __float_as_int(v));
    }
  }
  __syncthreads();
  for (int idx = tid; idx < 2 * BN; idx += 256) {
    const int s = (idx >= BN) ? 1 : 0;
    const int c = idx - s * BN;
    const int gg = g0 + s;
    if (gg < gTot && c < M)
      atomicMax(pooled + (size_t)gg * ldp + c, Ps[s][c]);
  }
}

// ---------------- tail GEMM tile (32x64, 4 waves split K in-block) ----------------
struct GJob {
  const void* A; const ushort* Bt; void* C; const float* bias;
  int lda, a_f32, ldbt, ldc, Nr, Kpad, M, relu, obf, rsplit, cpad, rb, cb, blk0;
};

__device__ void tail_tile(const GJob& j, int local, char* smem) {
  const int by = local / j.cb, bx = local - by * j.cb;
  const int row0 = by * 32, col0 = bx * 64;
  const int tid = threadIdx.x, lane = tid & 63, w = tid >> 6;

  ushort (*Asl)[32][40] = (ushort (*)[32][40])smem;           // 10240 B
  ushort (*Bsl)[64][40] = (ushort (*)[64][40])(smem + 10240); // 20480 B
  float  (*Rs)[32][64]  = (float  (*)[32][64])smem;           // 32768 B (aliased)

  const int a_r = lane >> 1, a_h = lane & 1;
  const int lm = lane & 15, lq = (lane >> 4) * 8;
  const int nst = j.Kpad / 32;

  uint4 ra[4], rb[4];
  auto gload = [&](int t) {
    const int k0 = t * 32;
    const int ar = row0 + a_r;
    if (j.a_f32) {
      if (ar < j.Nr) {
        const uint4* p = (const uint4*)((const float*)j.A + (size_t)ar * j.lda + k0 + a_h * 16);
        ra[0] = p[0]; ra[1] = p[1]; ra[2] = p[2]; ra[3] = p[3];
      } else {
        ra[0] = make_uint4(0u, 0u, 0u, 0u); ra[1] = ra[0]; ra[2] = ra[0]; ra[3] = ra[0];
      }
    } else {
      if (ar < j.Nr) {
        const uint4* p = (const uint4*)((const ushort*)j.A + (size_t)ar * j.lda + k0 + a_h * 16);
        ra[0] = p[0]; ra[1] = p[1];
      } else {
        ra[0] = make_uint4(0u, 0u, 0u, 0u); ra[1] = ra[0];
      }
    }
    const uint4* q = (const uint4*)(j.Bt + (size_t)(col0 + lane) * j.ldbt + k0);
    rb[0] = q[0]; rb[1] = q[1]; rb[2] = q[2]; rb[3] = q[3];
  };
  auto commit = [&]() {
    if (j.a_f32) {
      ushort tmp[16];
      const float* f = (const float*)&ra[0];
#pragma unroll
      for (int q2 = 0; q2 < 16; ++q2) tmp[q2] = f2b(f[q2]);
      *(uint4*)&Asl[w][a_r][a_h * 16]     = *(uint4*)&tmp[0];
      *(uint4*)&Asl[w][a_r][a_h * 16 + 8] = *(uint4*)&tmp[8];
    } else {
      *(uint4*)&Asl[w][a_r][a_h * 16]     = ra[0];
      *(uint4*)&Asl[w][a_r][a_h * 16 + 8] = ra[1];
    }
    *(uint4*)&Bsl[w][lane][0]  = rb[0];
    *(uint4*)&Bsl[w][lane][8]  = rb[1];
    *(uint4*)&Bsl[w][lane][16] = rb[2];
    *(uint4*)&Bsl[w][lane][24] = rb[3];
  };

  f32x4 acc[2][4] = {};
  if (w < nst) {
    gload(w);
    for (int t = w; t < nst; t += 4) {
      commit();
      bf16x8 af0 = *(const bf16x8*)&Asl[w][lm][lq];
      bf16x8 af1 = *(const bf16x8*)&Asl[w][16 + lm][lq];
      bf16x8 bq0 = *(const bf16x8*)&Bsl[w][lm][lq];
      bf16x8 bq1 = *(const bf16x8*)&Bsl[w][16 + lm][lq];
      bf16x8 bq2 = *(const bf16x8*)&Bsl[w][32 + lm][lq];
      bf16x8 bq3 = *(const bf16x8*)&Bsl[w][48 + lm][lq];
      if (t + 4 < nst) gload(t + 4);
      acc[0][0] = __builtin_amdgcn_mfma_f32_16x16x32_bf16(af0, bq0, acc[0][0], 0, 0, 0);
      acc[0][1] = __builtin_amdgcn_mfma_f32_16x16x32_bf16(af0, bq1, acc[0][1], 0, 0, 0);
      acc[0][2] = __builtin_amdgcn_mfma_f32_16x16x32_bf16(af0, bq2, acc[0][2], 0, 0, 0);
      acc[0][3] = __builtin_amdgcn_mfma_f32_16x16x32_bf16(af0, bq3, acc[0][3], 0, 0, 0);
      acc[1][0] = __builtin_amdgcn_mfma_f32_16x16x32_bf16(af1, bq0, acc[1][0], 0, 0, 0);
      acc[1][1] = __builtin_amdgcn_mfma_f32_16x16x32_bf16(af1, bq1, acc[1][1], 0, 0, 0);
      acc[1][2] = __builtin_amdgcn_mfma_f32_16x16x32_bf16(af1, bq2, acc[1][2], 0, 0, 0);
      acc[1][3] = __builtin_amdgcn_mfma_f32_16x16x32_bf16(af1, bq3, acc[1][3], 0, 0, 0);
    }
  }

  __syncthreads();  // staging done; alias as Rs
  const int rquad = (lane >> 4) * 4;
#pragma unroll
  for (int mt = 0; mt < 2; ++mt)
#pragma unroll
    for (int nt = 0; nt < 4; ++nt)
#pragma unroll
      for (int r = 0; r < 4; ++r)
        Rs[w][mt * 16 + rquad + r][nt * 16 + lm] = acc[mt][nt][r];
  __syncthreads();

  const int rrow = tid >> 3, cs = (tid & 7) * 8;
  float v[8];
  {
    float4 x0 = *(const float4*)&Rs[0][rrow][cs];
    float4 x1 = *(const float4*)&Rs[0][rrow][cs + 4];
    v[0] = x0.x; v[1] = x0.y; v[2] = x0.z; v[3] = x0.w;
    v[4] = x1.x; v[5] = x1.y; v[6] = x1.z; v[7] = x1.w;
  }
#pragma unroll
  for (int ww = 1; ww < 4; ++ww) {
    float4 x0 = *(const float4*)&Rs[ww][rrow][cs];
    float4 x1 = *(const float4*)&Rs[ww][rrow][cs + 4];
    v[0] += x0.x; v[1] += x0.y; v[2] += x0.z; v[3] += x0.w;
    v[4] += x1.x; v[5] += x1.y; v[6] += x1.z; v[7] += x1.w;
  }
  const int rg = row0 + rrow;
  if (rg < j.Nr) {
    int rm = rg, rq = 0;
    if (j.rsplit) { rq = rg / j.rsplit; rm = rg - rq * j.rsplit; }
#pragma unroll
    for (int q = 0; q < 8; ++q) {
      const int cc = col0 + cs + q;
      if (cc >= j.cpad) break;
      float x = 0.f;
      if (cc < j.M) {
        x = v[q] + j.bias[cc];
        if (j.relu) x = fmaxf(x, 0.f);
      }
      const size_t di = (size_t)rm * j.ldc + (size_t)rq * j.M + cc;
      if (j.obf) ((ushort*)j.C)[di] = f2b(x);
      else       ((float*)j.C)[di] = x;
    }
  }
  __syncthreads();  // protect smem reuse by next tile
}

// ---------------- cooperative MLP tail: 6 GEMM levels + Wo, one dispatch ----------------
struct TailArgs {
  GJob j[8];
  const float* wf3o; const float* Wo; const float* bo; float* out;
};

__launch_bounds__(256)
__global__ void mlp_tail(TailArgs ta) {
  __shared__ __align__(16) char smem[32768];
  cg::grid_group grid = cg::this_grid();
  const int lv_lo[6] = {0, 2, 4, 5, 6, 7};
  const int lv_hi[6] = {2, 4, 5, 6, 7, 8};
  for (int lv = 0; lv < 6; ++lv) {
    int tot = 0;
    for (int ji = lv_lo[lv]; ji < lv_hi[lv]; ++ji) tot += ta.j[ji].rb * ta.j[ji].cb;
    for (int t = blockIdx.x; t < tot; t += gridDim.x) {
      int ji = lv_lo[lv], rem = t;
      while (rem >= ta.j[ji].rb * ta.j[ji].cb) { rem -= ta.j[ji].rb * ta.j[ji].cb; ++ji; }
      tail_tile(ta.j[ji], rem, smem);
    }
    grid.sync();
  }
  // Wo: out[256][2] = wf3o[256][128] @ Wo[128][2] + bo
  const int gid = blockIdx.x * 256 + threadIdx.x;
  if (gid < N_GRAPH * 2) {
    const int row = gid >> 1, col = gid & 1;
    float v = ta.bo[col];
    const float* a = ta.wf3o + (size_t)row * 128;
    for (int k = 0; k < 128; ++k) v += a[k] * ta.Wo[k * 2 + col];
    ta.out[gid] = v;
  }
}

// ---------------- one-shot prep: weight transposes + rownorm + edge scatter ----------------
struct WJob { const float* W; ushort* T; int Mv, Kv, Mp, Kp, blk0; };
struct WArgs {
  WJob j[11]; int wblocks; const float* cell; ushort* cv;
  const int* e1; const int* e2; int* cnt; ushort* col; int E, npass, rng, scatB;
};

__launch_bounds__(256)
__global__ void prep_all(WArgs a) {
  const int bid = blockIdx.x, tid = threadIdx.x;
  if (bid < a.wblocks) {
    __shared__ float t[32][33];
    int ji = 0;
#pragma unroll
    for (int i = 1; i < 11; ++i)
      if (bid >= a.j[i].blk0) ji = i;
    WJob wj = a.j[ji];
    const int lt = bid - wj.blk0;
    const int ktiles = wj.Kp >> 5;
    const int tn = lt / ktiles, tk = lt - tn * ktiles;
    const int n0 = tn << 5, k0 = tk << 5;
    const int c = tid & 31, r = tid >> 5;
    const int nn = n0 + c;
#pragma unroll
    for (int i = 0; i < 4; ++i) {
      const int k = k0 + r + i * 8;
      t[r + i * 8][c] = (k < wj.Kv && nn < wj.Mv) ? wj.W[(size_t)k * wj.Mv + nn] : 0.f;
    }
    __syncthreads();
    const int k = k0 + c;
#pragma unroll
    for (int i = 0; i < 4; ++i) {
      const int n = n0 + r + i * 8;
      wj.T[(size_t)n * wj.Kp + k] = f2b(t[c][r + i * 8]);
    }
    return;
  }
  if (bid < a.wblocks + N_GRAPH) {
    __shared__ float red[256];
    const int g = bid - a.wblocks;
    const float* row = a.cell + (size_t)g * 954;
    float s = 0.f;
    for (int f = tid; f < 954; f += 256) { float vv = row[f]; s += vv * vv; }
    red[tid] = s;
    __syncthreads();
    for (int off2 = 128; off2 > 0; off2 >>= 1) {
      if (tid < off2) red[tid] += red[tid + off2];
      __syncthreads();
    }
    const float inv = 1.f / fmaxf(sqrtf(red[0]), 1e-12f);
    ushort* orow = a.cv + (size_t)g * 960;
    for (int f = tid; f < 954; f += 256) orow[f] = f2b(row[f] * inv);
    for (int f = 954 + tid; f < 960; f += 256) orow[f] = 0;
    return;
  }
  // bucketed edge scatter (batched path; cnt pre-zeroed)
  const int sb = bid - a.wblocks - N_GRAPH;
  const int xcd = sb & 7;
  const int lo = xcd * a.rng, hi = lo + a.rng;
  const int base = (sb >> 3) * ECHUNK;
  const int TE = a.npass * a.E;
  for (int i = tid; i < ECHUNK; i += 256) {
    int e = base + i;
    if (e >= TE) break;
    int d, s;
    if (e < a.E) { d = a.e1[a.E + e]; s = a.e1[e]; }
    else { int jj = e - a.E; d = N_NODES + a.e2[a.E + jj]; s = N_NODES + a.e2[jj]; }
    if (d >= lo && d < hi) {
      int p = atomicAdd(&a.cnt[d], 1);
      if (p < DCAP) a.col[((size_t)d << 6) + p] = (ushort)s;
    }
  }
}

// standalone scatter (non-batched second pass)
__global__ void scatterb_kernel(const int* __restrict__ e1, const int* __restrict__ e2,
                                int* __restrict__ cnt, ushort* __restrict__ col_idx,
                                int E, int npass, int rng) {
  const int xcd = blockIdx.x & 7;
  const int lo = xcd * rng, hi = lo + rng;
  const int base = (blockIdx.x >> 3) * ECHUNK;
  const int TE = npass * E;
  for (int i = threadIdx.x; i < ECHUNK; i += 256) {
    int e = base + i;
    if (e >= TE) break;
    int d, s;
    if (e < E) { d = e1[E + e]; s = e1[e]; }
    else { int jj = e - E; d = N_NODES + e2[E + jj]; s = N_NODES + e2[jj]; }
    if (d >= lo && d < hi) {
      int p = atomicAdd(&cnt[d], 1);
      if (p < DCAP) col_idx[((size_t)d << 6) + p] = (ushort)s;
    }
  }
}

// dinv = rsqrt(deg+1), x -> bf16 prescaled by dinv (ld 80, pads zeroed)
__global__ void dinv_cvt_kernel(const int* __restrict__ cnt, float* __restrict__ dinv,
                                const float* __restrict__ xa, const float* __restrict__ xb,
                                int nsplit, ushort* __restrict__ dst, int total) {
  int gid = blockIdx.x * blockDim.x + threadIdx.x;
  if (gid >= total) return;
  int n = gid / 10, v = gid - n * 10;
  const float sc = rsqrtf((float)(cnt[n] + 1));
  if (v == 0) dinv[n] = sc;
  const float* src = (n < nsplit) ? xa + (size_t)n * 78 : xb + (size_t)(n - nsplit) * 78;
  const int f0 = v * 8;
  ushort o[8];
#pragma unroll
  for (int jj = 0; jj < 8; ++jj)
    o[jj] = (f0 + jj < 78) ? f2b(src[f0 + jj] * sc) : 0;
  ((uint4*)(dst + (size_t)n * 80))[v] = *(uint4*)o;
}

// ------------------------- launcher -------------------------
extern "C" void kernel_launch(void* const* d_in, const int* in_sizes, int n_in,
                              void* d_out, int out_size, void* d_ws, size_t ws_size,
                              hipStream_t stream) {
  (void)in_sizes; (void)n_in; (void)out_size;
  const float* x1  = (const float*)d_in[0];
  const int*   ei1 = (const int*)d_in[1];
  const int*   bt1 = (const int*)d_in[2];
  const float* x2  = (const float*)d_in[3];
  const int*   ei2 = (const int*)d_in[4];
  const int*   bt2 = (const int*)d_in[5];
  const float* cell = (const float*)d_in[6];
  const float* Wc1 = (const float*)d_in[7];  const float* bc1 = (const float*)d_in[8];
  const float* Wc2 = (const float*)d_in[9];  const float* bc2 = (const float*)d_in[10];
  const float* Wc3 = (const float*)d_in[11]; const float* bc3 = (const float*)d_in[12];
  const float* Wg1 = (const float*)d_in[13]; const float* bg1 = (const float*)d_in[14];
  const float* Wg2 = (const float*)d_in[15]; const float* bg2 = (const float*)d_in[16];
  const float* Wr1 = (const float*)d_in[17]; const float* br1 = (const float*)d_in[18];
  const float* Wr2 = (const float*)d_in[19]; const float* br2 = (const float*)d_in[20];
  const float* Wr3 = (const float*)d_in[21]; const float* br3 = (const float*)d_in[22];
  const float* Wf1 = (const float*)d_in[23]; const float* bf1 = (const float*)d_in[24];
  const float* Wf2 = (const float*)d_in[25]; const float* bf2 = (const float*)d_in[26];
  const float* Wf3 = (const float*)d_in[27]; const float* bf3 = (const float*)d_in[28];
  const float* Wo  = (const float*)d_in[29]; const float* bo  = (const float*)d_in[30];
  float* out = (float*)d_out;

  const bool batched = ws_size >= (size_t)95 * 1024 * 1024;
  const int NN = batched ? 2 * N_NODES : N_NODES;
  const int NPASS = batched ? 2 : 1;
  const int NNW = NPASS * N_NODES;

  char* ws = (char*)d_ws;
  size_t off = 0;
  auto alloc_f = [&](size_t ne) {
    ne = (ne + 3) & ~(size_t)3;
    float* p = (float*)(ws + off); off += ne * 4; return p;
  };
  auto alloc_i = [&](size_t ne) {
    ne = (ne + 3) & ~(size_t)3;
    int* p = (int*)(ws + off); off += ne * 4; return p;
  };
  ushort* xb16w = (ushort*)alloc_f((size_t)NNW * 80);  // bf16 prescaled h, ld 160 (L2 out)
  ushort* ab16  = (ushort*)alloc_f((size_t)NNW * 40);  // L1 out, ld 80
  ushort* xb16s = (ushort*)alloc_f((size_t)NNW * 40);  // bf16 prescaled x, ld 80
  float* dinv   = alloc_f(NNW);
  int* cnt      = alloc_i(NNW);                         // cnt+pooled contiguous: 1 memset
  float* pooled = alloc_f((size_t)512 * 320);           // fp32 (atomicMax int-bits), ld 320
  ushort* cv16  = (ushort*)alloc_f((size_t)N_GRAPH * 480);   // bf16 cell, ld 960
  ushort* wg1o  = (ushort*)alloc_f((size_t)512 * 80);        // bf16, ld 160
  ushort* wr1o  = (ushort*)alloc_f((size_t)256 * 1024);      // bf16, ld 2048
  ushort* wr2o  = (ushort*)alloc_f((size_t)256 * 256);       // bf16, ld 512
  ushort* catbuf = (ushort*)alloc_f((size_t)256 * 256);      // bf16, ld 512
  ushort* wf1o  = (ushort*)alloc_f((size_t)256 * 512);       // bf16, ld 1024
  ushort* wf2o  = (ushort*)alloc_f((size_t)256 * 256);       // bf16, ld 512
  float* wf3o   = alloc_f((size_t)256 * 128);                // fp32, ld 128
  ushort* wc1t  = (ushort*)alloc_f(128 * 96 / 2);
  ushort* wc2t  = (ushort*)alloc_f(192 * 96 / 2);
  ushort* wc3t  = (ushort*)alloc_f(384 * 160 / 2);
  ushort* wr1t  = (ushort*)alloc_f(2048 * 960 / 2);
  ushort* wr2t  = (ushort*)alloc_f(512 * 2048 / 2);
  ushort* wf1t  = (ushort*)alloc_f(1024 * 512 / 2);
  ushort* wg1t  = (ushort*)alloc_f(192 * 320 / 2);
  ushort* wg2t  = (ushort*)alloc_f(128 * 160 / 2);
  ushort* wr3t  = (ushort*)alloc_f(256 * 512 / 2);
  ushort* wf2t  = (ushort*)alloc_f(512 * 1024 / 2);
  ushort* wf3t  = (ushort*)alloc_f(128 * 512 / 2);
  ushort* col_idx = (ushort*)alloc_i((size_t)NN * DCAP / 2);
  (void)NN;

  auto mkjob = [&](const void* A, int lda, int a_f32, const ushort* Bt, int ldbt,
                   void* C, int ldc, const float* bias, int Nr, int Kpad, int M,
                   int relu, int obf, int rsplit, int cpad) {
    GJob g; g.A = A; g.Bt = Bt; g.C = C; g.bias = bias;
    g.lda = lda; g.a_f32 = a_f32; g.ldbt = ldbt; g.ldc = ldc;
    g.Nr = Nr; g.Kpad = Kpad; g.M = M; g.relu = relu; g.obf = obf;
    g.rsplit = rsplit; g.cpad = cpad;
    g.rb = (Nr + 31) / 32; g.cb = (M + 63) / 64; g.blk0 = 0;
    return g;
  };

  // prep args: 11 weight transposes + rownorm (+ batched scatter)
  WArgs wa{};
  int wb = 0;
  {
    int nj = 0;
    auto addw = [&](const float* W, ushort* T, int Mv, int Kv, int Mp, int Kp) {
      wa.j[nj].W = W; wa.j[nj].T = T; wa.j[nj].Mv = Mv; wa.j[nj].Kv = Kv;
      wa.j[nj].Mp = Mp; wa.j[nj].Kp = Kp; wa.j[nj].blk0 = wb;
      wb += (Mp >> 5) * (Kp >> 5); ++nj;
    };
    addw(Wc1, wc1t,   78,   78,  128,   96);
    addw(Wc2, wc2t,  156,   78,  192,   96);
    addw(Wc3, wc3t,  312,  156,  384,  160);
    addw(Wr1, wr1t, 2048,  954, 2048,  960);
    addw(Wr2, wr2t,  512, 2048,  512, 2048);
    addw(Wf1, wf1t, 1024,  512, 1024,  512);
    addw(Wg1, wg1t,  156,  312,  192,  320);
    addw(Wg2, wg2t,  128,  156,  128,  160);
    addw(Wr3, wr3t,  256,  512,  256,  512);
    addw(Wf2, wf2t,  512, 1024,  512, 1024);
    addw(Wf3, wf3t,  128,  512,  128,  512);
    wa.wblocks = wb; wa.cell = cell; wa.cv = cv16;
  }

  auto node_layers = [&](const float* xa, const float* xb,
                         const int* bta, const int* btb, int npass, int pool_base) {
    const int nn = npass * N_NODES;
    {
      int tot = nn * 10;
      dinv_cvt_kernel<<<(tot + 255) / 256, 256, 0, stream>>>(
          cnt, dinv, xa, xb, (npass == 2) ? N_NODES : nn, xb16s, tot);
    }
    const int R = (nn + 63) / 64, RR = (R + 7) >> 3;
    dim3 fgrid(8 * RR, 1, 1);
    // layer 1: fused agg+GEMM 78->78 (Kpad 96), out ab16 ld80 (prescaled bf16)
    gemm_fused<8><<<fgrid, 256, 0, stream>>>(xb16s, cnt, col_idx, dinv, wc1t, 96,
                                             ab16, 80, bc1, nn, 78, 80);
    // layer 2: fused agg+GEMM 78->156, out xb16w ld160 (prescaled bf16)
    gemm_fused<12><<<fgrid, 256, 0, stream>>>(ab16, cnt, col_idx, dinv, wc2t, 96,
                                              xb16w, 160, bc2, nn, 156, 160);
    // layer 3: fused agg+GEMM 156->312 (Kpad 160) + segment-max pool
    gemm_fused3<<<fgrid, 256, 0, stream>>>(xb16w, cnt, col_idx, dinv, wc3t, 160,
                                           (int*)pooled, 320, bc3, nn, 312,
                                           bta, btb, (npass == 2) ? N_NODES : nn,
                                           pool_base, pool_base + N_GRAPH,
                                           pool_base + npass * N_GRAPH);
  };

  if (batched) {
    const int echunks = (2 * N_EDGES + ECHUNK - 1) / ECHUNK;
    hipMemsetAsync(cnt, 0, (size_t)NNW * 4 + (size_t)512 * 320 * 4, stream);
    wa.e1 = ei1; wa.e2 = ei2; wa.cnt = cnt; wa.col = col_idx;
    wa.E = N_EDGES; wa.npass = 2; wa.rng = NNW / 8; wa.scatB = 8 * echunks;
    prep_all<<<wb + N_GRAPH + wa.scatB, 256, 0, stream>>>(wa);
    node_layers(x1, x2, bt1, bt2, 2, 0);
  } else {
    wa.e1 = ei1; wa.e2 = ei1; wa.cnt = cnt; wa.col = col_idx;
    wa.E = N_EDGES; wa.npass = 1; wa.rng = N_NODES / 8; wa.scatB = 0;
    prep_all<<<wb + N_GRAPH, 256, 0, stream>>>(wa);
    const int echunks = (N_EDGES + ECHUNK - 1) / ECHUNK;
    hipMemsetAsync(cnt, 0, (size_t)N_NODES * 4 + (size_t)512 * 320 * 4, stream);
    scatterb_kernel<<<8 * echunks, 256, 0, stream>>>(ei1, ei1, cnt, col_idx,
                                                     N_EDGES, 1, N_NODES / 8);
    node_layers(x1, x1, bt1, bt1, 1, 0);
    hipMemsetAsync(cnt, 0, (size_t)N_NODES * 4, stream);
    scatterb_kernel<<<8 * echunks, 256, 0, stream>>>(ei2, ei2, cnt, col_idx,
                                                     N_EDGES, 1, N_NODES / 8);
    node_layers(x2, x2, bt2, bt2, 1, N_GRAPH);
  }

  // MLP tail: one cooperative dispatch, 6 GEMM levels + Wo
  {
    TailArgs ta{};
    ta.j[0] = mkjob(pooled, 320, 1, wg1t, 320, wg1o, 160, bg1, 512, 320, 156, 1, 1, 0, 160);
    ta.j[1] = mkjob(cv16,   960, 0, wr1t, 960, wr1o, 2048, br1, 256, 960, 2048, 1, 1, 0, 2048);
    ta.j[2] = mkjob(wg1o,  160, 0, wg2t,  160, catbuf, 512, bg2, 512,  160,  128, 0, 1, 256, 128);
    ta.j[3] = mkjob(wr1o, 2048, 0, wr2t, 2048, wr2o,   512, br2, 256, 2048,  512, 1, 1, 0, 512);
    ta.j[4] = mkjob(wr2o,  512, 0, wr3t,  512, catbuf + 256, 512, br3, 256, 512, 256, 1, 1, 0, 256);
    ta.j[5] = mkjob(catbuf, 512, 0, wf1t,  512, wf1o, 1024, bf1, 256,  512, 1024, 1, 1, 0, 1024);
    ta.j[6] = mkjob(wf1o,  1024, 0, wf2t, 1024, wf2o,  512, bf2, 256, 1024,  512, 1, 1, 0, 512);
    ta.j[7] = mkjob(wf2o,   512, 0, wf3t,  512, wf3o,  128, bf3, 256,  512,  128, 1, 0, 0, 128);
    ta.wf3o = wf3o; ta.Wo = Wo; ta.bo = bo; ta.out = out;
    void* kargs[] = { &ta };
    hipLaunchCooperativeKernel((void*)mlp_tail, dim3(256), dim3(256), kargs, 0, stream);
  }
}

// Round 8
// 414.089 us; speedup vs baseline: 1.5114x; 1.5114x over previous
//
#include <hip/hip_runtime.h>

#define N_NODES 20000
#define N_EDGES 320000
#define N_GRAPH 256
#define ECHUNK 2048
#define DCAP 64

__device__ __forceinline__ ushort f2b(float f) {  // fp32 -> bf16 RNE
  unsigned u = __float_as_uint(f);
  u += 0x7FFFu + ((u >> 16) & 1u);
  return (ushort)(u >> 16);
}
__device__ __forceinline__ float b2f(ushort u) {
  return __uint_as_float(((unsigned)u) << 16);
}

typedef __attribute__((ext_vector_type(8))) short bf16x8;
typedef __attribute__((ext_vector_type(4))) float f32x4;

// ---- bf16x8 accumulate helper (gather path) ----
__device__ __forceinline__ void acc8(float* a, uint4 u) {
  a[0] += __uint_as_float(u.x << 16);
  a[1] += __uint_as_float(u.x & 0xFFFF0000u);
  a[2] += __uint_as_float(u.y << 16);
  a[3] += __uint_as_float(u.y & 0xFFFF0000u);
  a[4] += __uint_as_float(u.z << 16);
  a[5] += __uint_as_float(u.z & 0xFFFF0000u);
  a[6] += __uint_as_float(u.w << 16);
  a[7] += __uint_as_float(u.w & 0xFFFF0000u);
}

// ---------------- FUSED agg + bf16 MFMA GEMM (layers 1 & 2) ----------------
// Gathers + sums dinv-prescaled neighbor rows of h (ld 80, 10 uint4 chunks)
// directly into the A-tile LDS (fp32 accum -> f2b), then the K=96 MFMA loop.
// Epilogue: bias + relu + dinv[row] prescale + bf16 store, zero cols [M,cwz).
template <int BN_T>  // BN = BN_T*16
__launch_bounds__(256)
__global__ void gemm_fused(const ushort* __restrict__ h,
                           const int* __restrict__ cnt,
                           const ushort* __restrict__ col_idx,
                           const float* __restrict__ dinv,
                           const ushort* __restrict__ Bt, int ldbt,
                           ushort* __restrict__ C, int ldc,
                           const float* __restrict__ bias,
                           int Nr, int M, int cwz) {
  constexpr int BM = 64, BN = BN_T * 16, LA = 104;
  __shared__ __align__(16) ushort Afull[BM][LA];
  __shared__ __align__(16) ushort Bsl[BN][40];
  const int tid = threadIdx.x;
  const int R = (Nr + BM - 1) / BM;
  const int RR = (R + 7) >> 3;
  const int xz = blockIdx.x & 7, g = blockIdx.x >> 3;
  const int by = xz * RR + g;
  if (by >= R) return;
  const int row0 = by * BM;
  const int lane = tid & 63, w = tid >> 6;
  const uint4* hv = (const uint4*)h;

  for (int task = tid; task < BM * 10; task += 256) {
    const int r = task / 10, c = task - r * 10;
    const int n = row0 + r;
    uint4 val = make_uint4(0u, 0u, 0u, 0u);
    if (n < Nr) {
      float a[8] = {};
      acc8(a, hv[(size_t)n * 10 + c]);  // self (prescaled)
      const int beg = n << 6;
      const int end = beg + min(cnt[n], DCAP);
      int e = beg;
      for (; e + 3 < end; e += 4) {
        int s0 = col_idx[e], s1 = col_idx[e + 1];
        int s2 = col_idx[e + 2], s3 = col_idx[e + 3];
        acc8(a, hv[(size_t)s0 * 10 + c]); acc8(a, hv[(size_t)s1 * 10 + c]);
        acc8(a, hv[(size_t)s2 * 10 + c]); acc8(a, hv[(size_t)s3 * 10 + c]);
      }
      for (; e < end; ++e) acc8(a, hv[(size_t)col_idx[e] * 10 + c]);
      const float dn = dinv[n];
      ushort o[8];
#pragma unroll
      for (int j = 0; j < 8; ++j) o[j] = f2b(dn * a[j]);
      val = *(uint4*)o;
    }
    *(uint4*)&Afull[r][c * 8] = val;
  }
  for (int task = tid; task < BM * 2; task += 256) {
    const int r = task >> 1, c2 = task & 1;
    *(uint4*)&Afull[r][80 + c2 * 8] = make_uint4(0u, 0u, 0u, 0u);
  }
  __syncthreads();

  f32x4 acc[BN_T] = {};
  const int mrow = w * 16;
  const int lm = lane & 15, lq = (lane >> 4) * 8;
  for (int t = 0; t < 3; ++t) {
    const int k0 = t * 32;
    for (int s = tid; s < BN * 4; s += 256) {
      const int br = s >> 2, bo = (s & 3) * 8;
      *(uint4*)&Bsl[br][bo] = *(const uint4*)&Bt[(size_t)br * ldbt + k0 + bo];
    }
    __syncthreads();
    bf16x8 af = *(const bf16x8*)&Afull[mrow + lm][k0 + lq];
#pragma unroll
    for (int nt = 0; nt < BN_T; ++nt) {
      bf16x8 bf = *(const bf16x8*)&Bsl[nt * 16 + lm][lq];
      acc[nt] = __builtin_amdgcn_mfma_f32_16x16x32_bf16(af, bf, acc[nt], 0, 0, 0);
    }
    __syncthreads();
  }

  const int rquad = (lane >> 4) * 4;
#pragma unroll
  for (int nt = 0; nt < BN_T; ++nt) {
    const int cc = nt * 16 + lm;
    if (cc >= cwz) continue;
    const bool cval = cc < M;
    const float bv = cval ? bias[cc] : 0.f;
#pragma unroll
    for (int r = 0; r < 4; ++r) {
      const int rr = row0 + mrow + rquad + r;
      if (rr >= Nr) continue;
      float v = cval ? fmaxf(acc[nt][r] + bv, 0.f) * dinv[rr] : 0.f;
      C[(size_t)rr * ldc + cc] = f2b(v);
    }
  }
}

// ---------------- FUSED agg + GEMM + segment-max pool (layer 3) ----------------
// h = xb16w (ld 160, 20 uint4 chunks, cols 156..159 zero). Full N=312 in one
// block (acc[20]); gather once; pool epilogue (<=2 graphs per 64-row tile).
__launch_bounds__(256)
__global__ void gemm_fused3(const ushort* __restrict__ h,
                            const int* __restrict__ cnt,
                            const ushort* __restrict__ col_idx,
                            const float* __restrict__ dinv,
                            const ushort* __restrict__ Bt, int ldbt,
                            int* __restrict__ pooled, int ldp,
                            const float* __restrict__ bias,
                            int Nr, int M,
                            const int* __restrict__ bA, const int* __restrict__ bB,
                            int nsplit, int gA, int gB, int gTot) {
  constexpr int BM = 64, BN = 320, LA = 168;
  __shared__ __align__(16) ushort Afull[BM][LA];   // 21504 B
  __shared__ __align__(16) ushort Bsl[BN][40];     // 25600 B
  __shared__ int Ps[2][BN];                        // 2560 B
  const int tid = threadIdx.x;
  const int R = (Nr + BM - 1) / BM;
  const int RR = (R + 7) >> 3;
  const int xz = blockIdx.x & 7, g = blockIdx.x >> 3;
  const int by = xz * RR + g;
  if (by >= R) return;
  const int row0 = by * BM;
  const int lane = tid & 63, w = tid >> 6;
  const uint4* hv = (const uint4*)h;

  for (int task = tid; task < BM * 20; task += 256) {
    const int r = task / 20, c = task - r * 20;
    const int n = row0 + r;
    uint4 val = make_uint4(0u, 0u, 0u, 0u);
    if (n < Nr) {
      float a[8] = {};
      acc8(a, hv[(size_t)n * 20 + c]);  // self (prescaled)
      const int beg = n << 6;
      const int end = beg + min(cnt[n], DCAP);
      int e = beg;
      for (; e + 3 < end; e += 4) {
        int s0 = col_idx[e], s1 = col_idx[e + 1];
        int s2 = col_idx[e + 2], s3 = col_idx[e + 3];
        acc8(a, hv[(size_t)s0 * 20 + c]); acc8(a, hv[(size_t)s1 * 20 + c]);
        acc8(a, hv[(size_t)s2 * 20 + c]); acc8(a, hv[(size_t)s3 * 20 + c]);
      }
      for (; e < end; ++e) acc8(a, hv[(size_t)col_idx[e] * 20 + c]);
      const float dn = dinv[n];
      ushort o[8];
#pragma unroll
      for (int j = 0; j < 8; ++j) o[j] = f2b(dn * a[j]);
      val = *(uint4*)o;
    }
    *(uint4*)&Afull[r][c * 8] = val;
  }
  for (int idx = tid; idx < 2 * BN; idx += 256) ((int*)Ps)[idx] = 0;
  __syncthreads();

  f32x4 acc[20] = {};
  const int mrow = w * 16;
  const int lm = lane & 15, lq = (lane >> 4) * 8;
  for (int t = 0; t < 5; ++t) {
    const int k0 = t * 32;
    for (int s = tid; s < BN * 4; s += 256) {
      const int br = s >> 2, bo = (s & 3) * 8;
      *(uint4*)&Bsl[br][bo] = *(const uint4*)&Bt[(size_t)br * ldbt + k0 + bo];
    }
    __syncthreads();
    bf16x8 af = *(const bf16x8*)&Afull[mrow + lm][k0 + lq];
#pragma unroll
    for (int nt = 0; nt < 20; ++nt) {
      bf16x8 bf = *(const bf16x8*)&Bsl[nt * 16 + lm][lq];
      acc[nt] = __builtin_amdgcn_mfma_f32_16x16x32_bf16(af, bf, acc[nt], 0, 0, 0);
    }
    __syncthreads();
  }

  const int rquad = (lane >> 4) * 4;
  const int g0 = (row0 < nsplit) ? gA + bA[row0] : gB + bB[row0 - nsplit];
  int gr[4];
#pragma unroll
  for (int r = 0; r < 4; ++r) {
    const int rr = row0 + mrow + rquad + r;
    gr[r] = (rr < Nr) ? ((rr < nsplit) ? gA + bA[rr] : gB + bB[rr - nsplit]) - g0 : -1;
  }
#pragma unroll
  for (int nt = 0; nt < 20; ++nt) {
    const int cc = nt * 16 + lm;
    if (cc >= M) continue;
    const float bv = bias[cc];
#pragma unroll
    for (int r = 0; r < 4; ++r) {
      if (gr[r] < 0) continue;
      const float v = fmaxf(acc[nt][r] + bv, 0.f);
      atomicMax(&Ps[gr[r]][cc], __float_as_int(v));
    }
  }
  __syncthreads();
  for (int idx = tid; idx < 2 * BN; idx += 256) {
    const int s = (idx >= BN) ? 1 : 0;
    const int c = idx - s * BN;
    const int gg = g0 + s;
    if (gg < gTot && c < M)
      atomicMax(pooled + (size_t)gg * ldp + c, Ps[s][c]);
  }
}

// ---------------- grouped small-GEMM: 32x64 tile, 4 waves split K in-block ----------------
struct GJob {
  const void* A; const ushort* Bt; void* C; const float* bias;
  int lda, a_f32, ldbt, ldc, Nr, Kpad, M, relu, obf, rsplit, cpad, rb, cb, blk0;
};

__launch_bounds__(256)
__global__ void gemm_grp(GJob j0, GJob j1, int njobs) {
  GJob j = (njobs > 1 && (int)blockIdx.x >= j1.blk0) ? j1 : j0;
  const int local = blockIdx.x - j.blk0;
  const int by = local / j.cb, bx = local - by * j.cb;
  const int row0 = by * 32, col0 = bx * 64;
  const int tid = threadIdx.x, lane = tid & 63, w = tid >> 6;

  __shared__ __align__(16) char smem[32768];
  ushort (*Asl)[32][40] = (ushort (*)[32][40])smem;           // 10240 B
  ushort (*Bsl)[64][40] = (ushort (*)[64][40])(smem + 10240); // 20480 B
  float  (*Rs)[32][64]  = (float  (*)[32][64])smem;           // 32768 B (aliased)

  const int a_r = lane >> 1, a_h = lane & 1;
  const int lm = lane & 15, lq = (lane >> 4) * 8;
  const int nst = j.Kpad / 32;

  uint4 ra[4], rb[4];
  auto gload = [&](int t) {
    const int k0 = t * 32;
    const int ar = row0 + a_r;
    if (j.a_f32) {
      if (ar < j.Nr) {
        const uint4* p = (const uint4*)((const float*)j.A + (size_t)ar * j.lda + k0 + a_h * 16);
        ra[0] = p[0]; ra[1] = p[1]; ra[2] = p[2]; ra[3] = p[3];
      } else {
        ra[0] = make_uint4(0u, 0u, 0u, 0u); ra[1] = ra[0]; ra[2] = ra[0]; ra[3] = ra[0];
      }
    } else {
      if (ar < j.Nr) {
        const uint4* p = (const uint4*)((const ushort*)j.A + (size_t)ar * j.lda + k0 + a_h * 16);
        ra[0] = p[0]; ra[1] = p[1];
      } else {
        ra[0] = make_uint4(0u, 0u, 0u, 0u); ra[1] = ra[0];
      }
    }
    const uint4* q = (const uint4*)(j.Bt + (size_t)(col0 + lane) * j.ldbt + k0);
    rb[0] = q[0]; rb[1] = q[1]; rb[2] = q[2]; rb[3] = q[3];
  };
  auto commit = [&]() {
    if (j.a_f32) {
      ushort tmp[16];
      const float* f = (const float*)&ra[0];
#pragma unroll
      for (int q2 = 0; q2 < 16; ++q2) tmp[q2] = f2b(f[q2]);
      *(uint4*)&Asl[w][a_r][a_h * 16]     = *(uint4*)&tmp[0];
      *(uint4*)&Asl[w][a_r][a_h * 16 + 8] = *(uint4*)&tmp[8];
    } else {
      *(uint4*)&Asl[w][a_r][a_h * 16]     = ra[0];
      *(uint4*)&Asl[w][a_r][a_h * 16 + 8] = ra[1];
    }
    *(uint4*)&Bsl[w][lane][0]  = rb[0];
    *(uint4*)&Bsl[w][lane][8]  = rb[1];
    *(uint4*)&Bsl[w][lane][16] = rb[2];
    *(uint4*)&Bsl[w][lane][24] = rb[3];
  };

  f32x4 acc[2][4] = {};
  if (w < nst) {
    gload(w);
    for (int t = w; t < nst; t += 4) {
      commit();
      bf16x8 af0 = *(const bf16x8*)&Asl[w][lm][lq];
      bf16x8 af1 = *(const bf16x8*)&Asl[w][16 + lm][lq];
      bf16x8 bq0 = *(const bf16x8*)&Bsl[w][lm][lq];
      bf16x8 bq1 = *(const bf16x8*)&Bsl[w][16 + lm][lq];
      bf16x8 bq2 = *(const bf16x8*)&Bsl[w][32 + lm][lq];
      bf16x8 bq3 = *(const bf16x8*)&Bsl[w][48 + lm][lq];
      if (t + 4 < nst) gload(t + 4);
      acc[0][0] = __builtin_amdgcn_mfma_f32_16x16x32_bf16(af0, bq0, acc[0][0], 0, 0, 0);
      acc[0][1] = __builtin_amdgcn_mfma_f32_16x16x32_bf16(af0, bq1, acc[0][1], 0, 0, 0);
      acc[0][2] = __builtin_amdgcn_mfma_f32_16x16x32_bf16(af0, bq2, acc[0][2], 0, 0, 0);
      acc[0][3] = __builtin_amdgcn_mfma_f32_16x16x32_bf16(af0, bq3, acc[0][3], 0, 0, 0);
      acc[1][0] = __builtin_amdgcn_mfma_f32_16x16x32_bf16(af1, bq0, acc[1][0], 0, 0, 0);
      acc[1][1] = __builtin_amdgcn_mfma_f32_16x16x32_bf16(af1, bq1, acc[1][1], 0, 0, 0);
      acc[1][2] = __builtin_amdgcn_mfma_f32_16x16x32_bf16(af1, bq2, acc[1][2], 0, 0, 0);
      acc[1][3] = __builtin_amdgcn_mfma_f32_16x16x32_bf16(af1, bq3, acc[1][3], 0, 0, 0);
    }
  }

  __syncthreads();  // all waves done with staging LDS; safe to alias as Rs
  const int rquad = (lane >> 4) * 4;
#pragma unroll
  for (int mt = 0; mt < 2; ++mt)
#pragma unroll
    for (int nt = 0; nt < 4; ++nt)
#pragma unroll
      for (int r = 0; r < 4; ++r)
        Rs[w][mt * 16 + rquad + r][nt * 16 + lm] = acc[mt][nt][r];
  __syncthreads();

  const int rrow = tid >> 3, cs = (tid & 7) * 8;
  float v[8];
  {
    float4 x0 = *(const float4*)&Rs[0][rrow][cs];
    float4 x1 = *(const float4*)&Rs[0][rrow][cs + 4];
    v[0] = x0.x; v[1] = x0.y; v[2] = x0.z; v[3] = x0.w;
    v[4] = x1.x; v[5] = x1.y; v[6] = x1.z; v[7] = x1.w;
  }
#pragma unroll
  for (int ww = 1; ww < 4; ++ww) {
    float4 x0 = *(const float4*)&Rs[ww][rrow][cs];
    float4 x1 = *(const float4*)&Rs[ww][rrow][cs + 4];
    v[0] += x0.x; v[1] += x0.y; v[2] += x0.z; v[3] += x0.w;
    v[4] += x1.x; v[5] += x1.y; v[6] += x1.z; v[7] += x1.w;
  }
  const int rg = row0 + rrow;
  if (rg < j.Nr) {
    int rm = rg, rq = 0;
    if (j.rsplit) { rq = rg / j.rsplit; rm = rg - rq * j.rsplit; }
#pragma unroll
    for (int q = 0; q < 8; ++q) {
      const int cc = col0 + cs + q;
      if (cc >= j.cpad) break;
      float x = 0.f;
      if (cc < j.M) {
        x = v[q] + j.bias[cc];
        if (j.relu) x = fmaxf(x, 0.f);
      }
      const size_t di = (size_t)rm * j.ldc + (size_t)rq * j.M + cc;
      if (j.obf) ((ushort*)j.C)[di] = f2b(x);
      else       ((float*)j.C)[di] = x;
    }
  }
}

// ---- final Wo layer: out[256][2] = wf3o[256][128] @ Wo[128][2] + bo ----
__global__ void wo_kernel(const float* __restrict__ wf3o, const float* __restrict__ Wo,
                          const float* __restrict__ bo, float* __restrict__ out) {
  int gid = blockIdx.x * blockDim.x + threadIdx.x;
  if (gid >= N_GRAPH * 2) return;
  int row = gid >> 1, col = gid & 1;
  float v = bo[col];
  const float* a = wf3o + (size_t)row * 128;
  for (int k = 0; k < 128; ++k) v += a[k] * Wo[k * 2 + col];
  out[gid] = v;
}

// ---------------- one-shot prep: weight transposes + rownorm + edge scatter ----------------
struct WJob { const float* W; ushort* T; int Mv, Kv, Mp, Kp, blk0; };
struct WArgs {
  WJob j[11]; int wblocks; const float* cell; ushort* cv;
  const int* e1; const int* e2; int* cnt; ushort* col; int E, npass, rng, scatB;
};

__launch_bounds__(256)
__global__ void prep_all(WArgs a) {
  const int bid = blockIdx.x, tid = threadIdx.x;
  if (bid < a.wblocks) {
    __shared__ float t[32][33];
    int ji = 0;
#pragma unroll
    for (int i = 1; i < 11; ++i)
      if (bid >= a.j[i].blk0) ji = i;
    WJob wj = a.j[ji];
    const int lt = bid - wj.blk0;
    const int ktiles = wj.Kp >> 5;
    const int tn = lt / ktiles, tk = lt - tn * ktiles;
    const int n0 = tn << 5, k0 = tk << 5;
    const int c = tid & 31, r = tid >> 5;
    const int nn = n0 + c;
#pragma unroll
    for (int i = 0; i < 4; ++i) {
      const int k = k0 + r + i * 8;
      t[r + i * 8][c] = (k < wj.Kv && nn < wj.Mv) ? wj.W[(size_t)k * wj.Mv + nn] : 0.f;
    }
    __syncthreads();
    const int k = k0 + c;
#pragma unroll
    for (int i = 0; i < 4; ++i) {
      const int n = n0 + r + i * 8;
      wj.T[(size_t)n * wj.Kp + k] = f2b(t[c][r + i * 8]);
    }
    return;
  }
  if (bid < a.wblocks + N_GRAPH) {
    __shared__ float red[256];
    const int g = bid - a.wblocks;
    const float* row = a.cell + (size_t)g * 954;
    float s = 0.f;
    for (int f = tid; f < 954; f += 256) { float vv = row[f]; s += vv * vv; }
    red[tid] = s;
    __syncthreads();
    for (int off2 = 128; off2 > 0; off2 >>= 1) {
      if (tid < off2) red[tid] += red[tid + off2];
      __syncthreads();
    }
    const float inv = 1.f / fmaxf(sqrtf(red[0]), 1e-12f);
    ushort* orow = a.cv + (size_t)g * 960;
    for (int f = tid; f < 954; f += 256) orow[f] = f2b(row[f] * inv);
    for (int f = 954 + tid; f < 960; f += 256) orow[f] = 0;
    return;
  }
  // bucketed edge scatter (batched path; cnt pre-zeroed)
  const int sb = bid - a.wblocks - N_GRAPH;
  const int xcd = sb & 7;
  const int lo = xcd * a.rng, hi = lo + a.rng;
  const int base = (sb >> 3) * ECHUNK;
  const int TE = a.npass * a.E;
  for (int i = tid; i < ECHUNK; i += 256) {
    int e = base + i;
    if (e >= TE) break;
    int d, s;
    if (e < a.E) { d = a.e1[a.E + e]; s = a.e1[e]; }
    else { int jj = e - a.E; d = N_NODES + a.e2[a.E + jj]; s = N_NODES + a.e2[jj]; }
    if (d >= lo && d < hi) {
      int p = atomicAdd(&a.cnt[d], 1);
      if (p < DCAP) a.col[((size_t)d << 6) + p] = (ushort)s;
    }
  }
}

// standalone scatter (non-batched second pass)
__global__ void scatterb_kernel(const int* __restrict__ e1, const int* __restrict__ e2,
                                int* __restrict__ cnt, ushort* __restrict__ col_idx,
                                int E, int npass, int rng) {
  const int xcd = blockIdx.x & 7;
  const int lo = xcd * rng, hi = lo + rng;
  const int base = (blockIdx.x >> 3) * ECHUNK;
  const int TE = npass * E;
  for (int i = threadIdx.x; i < ECHUNK; i += 256) {
    int e = base + i;
    if (e >= TE) break;
    int d, s;
    if (e < E) { d = e1[E + e]; s = e1[e]; }
    else { int jj = e - E; d = N_NODES + e2[E + jj]; s = N_NODES + e2[jj]; }
    if (d >= lo && d < hi) {
      int p = atomicAdd(&cnt[d], 1);
      if (p < DCAP) col_idx[((size_t)d << 6) + p] = (ushort)s;
    }
  }
}

// dinv = rsqrt(deg+1), x -> bf16 prescaled by dinv (ld 80, pads zeroed)
__global__ void dinv_cvt_kernel(const int* __restrict__ cnt, float* __restrict__ dinv,
                                const float* __restrict__ xa, const float* __restrict__ xb,
                                int nsplit, ushort* __restrict__ dst, int total) {
  int gid = blockIdx.x * blockDim.x + threadIdx.x;
  if (gid >= total) return;
  int n = gid / 10, v = gid - n * 10;
  const float sc = rsqrtf((float)(cnt[n] + 1));
  if (v == 0) dinv[n] = sc;
  const float* src = (n < nsplit) ? xa + (size_t)n * 78 : xb + (size_t)(n - nsplit) * 78;
  const int f0 = v * 8;
  ushort o[8];
#pragma unroll
  for (int jj = 0; jj < 8; ++jj)
    o[jj] = (f0 + jj < 78) ? f2b(src[f0 + jj] * sc) : 0;
  ((uint4*)(dst + (size_t)n * 80))[v] = *(uint4*)o;
}

// ------------------------- launcher -------------------------
extern "C" void kernel_launch(void* const* d_in, const int* in_sizes, int n_in,
                              void* d_out, int out_size, void* d_ws, size_t ws_size,
                              hipStream_t stream) {
  (void)in_sizes; (void)n_in; (void)out_size;
  const float* x1  = (const float*)d_in[0];
  const int*   ei1 = (const int*)d_in[1];
  const int*   bt1 = (const int*)d_in[2];
  const float* x2  = (const float*)d_in[3];
  const int*   ei2 = (const int*)d_in[4];
  const int*   bt2 = (const int*)d_in[5];
  const float* cell = (const float*)d_in[6];
  const float* Wc1 = (const float*)d_in[7];  const float* bc1 = (const float*)d_in[8];
  const float* Wc2 = (const float*)d_in[9];  const float* bc2 = (const float*)d_in[10];
  const float* Wc3 = (const float*)d_in[11]; const float* bc3 = (const float*)d_in[12];
  const float* Wg1 = (const float*)d_in[13]; const float* bg1 = (const float*)d_in[14];
  const float* Wg2 = (const float*)d_in[15]; const float* bg2 = (const float*)d_in[16];
  const float* Wr1 = (const float*)d_in[17]; const float* br1 = (const float*)d_in[18];
  const float* Wr2 = (const float*)d_in[19]; const float* br2 = (const float*)d_in[20];
  const float* Wr3 = (const float*)d_in[21]; const float* br3 = (const float*)d_in[22];
  const float* Wf1 = (const float*)d_in[23]; const float* bf1 = (const float*)d_in[24];
  const float* Wf2 = (const float*)d_in[25]; const float* bf2 = (const float*)d_in[26];
  const float* Wf3 = (const float*)d_in[27]; const float* bf3 = (const float*)d_in[28];
  const float* Wo  = (const float*)d_in[29]; const float* bo  = (const float*)d_in[30];
  float* out = (float*)d_out;

  const bool batched = ws_size >= (size_t)95 * 1024 * 1024;
  const int NPASS = batched ? 2 : 1;
  const int NNW = NPASS * N_NODES;

  char* ws = (char*)d_ws;
  size_t off = 0;
  auto alloc_f = [&](size_t ne) {
    ne = (ne + 3) & ~(size_t)3;
    float* p = (float*)(ws + off); off += ne * 4; return p;
  };
  auto alloc_i = [&](size_t ne) {
    ne = (ne + 3) & ~(size_t)3;
    int* p = (int*)(ws + off); off += ne * 4; return p;
  };
  ushort* xb16w = (ushort*)alloc_f((size_t)NNW * 80);  // bf16 prescaled h, ld 160 (L2 out)
  ushort* ab16  = (ushort*)alloc_f((size_t)NNW * 40);  // L1 out, ld 80
  ushort* xb16s = (ushort*)alloc_f((size_t)NNW * 40);  // bf16 prescaled x, ld 80
  float* dinv   = alloc_f(NNW);
  int* cnt      = alloc_i(NNW);                         // cnt+pooled contiguous: 1 memset
  float* pooled = alloc_f((size_t)512 * 320);           // fp32 (atomicMax int-bits), ld 320
  ushort* cv16  = (ushort*)alloc_f((size_t)N_GRAPH * 480);   // bf16 cell, ld 960
  ushort* wg1o  = (ushort*)alloc_f((size_t)512 * 80);        // bf16, ld 160
  ushort* wr1o  = (ushort*)alloc_f((size_t)256 * 1024);      // bf16, ld 2048
  ushort* wr2o  = (ushort*)alloc_f((size_t)256 * 256);       // bf16, ld 512
  ushort* catbuf = (ushort*)alloc_f((size_t)256 * 256);      // bf16, ld 512
  ushort* wf1o  = (ushort*)alloc_f((size_t)256 * 512);       // bf16, ld 1024
  ushort* wf2o  = (ushort*)alloc_f((size_t)256 * 256);       // bf16, ld 512
  float* wf3o   = alloc_f((size_t)256 * 128);                // fp32, ld 128
  ushort* wc1t  = (ushort*)alloc_f(128 * 96 / 2);
  ushort* wc2t  = (ushort*)alloc_f(192 * 96 / 2);
  ushort* wc3t  = (ushort*)alloc_f(384 * 160 / 2);
  ushort* wr1t  = (ushort*)alloc_f(2048 * 960 / 2);
  ushort* wr2t  = (ushort*)alloc_f(512 * 2048 / 2);
  ushort* wf1t  = (ushort*)alloc_f(1024 * 512 / 2);
  ushort* wg1t  = (ushort*)alloc_f(192 * 320 / 2);
  ushort* wg2t  = (ushort*)alloc_f(128 * 160 / 2);
  ushort* wr3t  = (ushort*)alloc_f(256 * 512 / 2);
  ushort* wf2t  = (ushort*)alloc_f(512 * 1024 / 2);
  ushort* wf3t  = (ushort*)alloc_f(128 * 512 / 2);
  ushort* col_idx = (ushort*)alloc_i((size_t)NNW * DCAP / 2);

  auto mkjob = [&](const void* A, int lda, int a_f32, const ushort* Bt, int ldbt,
                   void* C, int ldc, const float* bias, int Nr, int Kpad, int M,
                   int relu, int obf, int rsplit, int cpad) {
    GJob g; g.A = A; g.Bt = Bt; g.C = C; g.bias = bias;
    g.lda = lda; g.a_f32 = a_f32; g.ldbt = ldbt; g.ldc = ldc;
    g.Nr = Nr; g.Kpad = Kpad; g.M = M; g.relu = relu; g.obf = obf;
    g.rsplit = rsplit; g.cpad = cpad;
    g.rb = (Nr + 31) / 32; g.cb = (M + 63) / 64; g.blk0 = 0;
    return g;
  };
  auto grp1 = [&](GJob a) {
    gemm_grp<<<a.rb * a.cb, 256, 0, stream>>>(a, a, 1);
  };
  auto grp2 = [&](GJob a, GJob b) {
    b.blk0 = a.rb * a.cb;
    gemm_grp<<<b.blk0 + b.rb * b.cb, 256, 0, stream>>>(a, b, 2);
  };

  // prep args: 11 weight transposes + rownorm (+ batched scatter)
  WArgs wa{};
  int wb = 0;
  {
    int nj = 0;
    auto addw = [&](const float* W, ushort* T, int Mv, int Kv, int Mp, int Kp) {
      wa.j[nj].W = W; wa.j[nj].T = T; wa.j[nj].Mv = Mv; wa.j[nj].Kv = Kv;
      wa.j[nj].Mp = Mp; wa.j[nj].Kp = Kp; wa.j[nj].blk0 = wb;
      wb += (Mp >> 5) * (Kp >> 5); ++nj;
    };
    addw(Wc1, wc1t,   78,   78,  128,   96);
    addw(Wc2, wc2t,  156,   78,  192,   96);
    addw(Wc3, wc3t,  312,  156,  384,  160);
    addw(Wr1, wr1t, 2048,  954, 2048,  960);
    addw(Wr2, wr2t,  512, 2048,  512, 2048);
    addw(Wf1, wf1t, 1024,  512, 1024,  512);
    addw(Wg1, wg1t,  156,  312,  192,  320);
    addw(Wg2, wg2t,  128,  156,  128,  160);
    addw(Wr3, wr3t,  256,  512,  256,  512);
    addw(Wf2, wf2t,  512, 1024,  512, 1024);
    addw(Wf3, wf3t,  128,  512,  128,  512);
    wa.wblocks = wb; wa.cell = cell; wa.cv = cv16;
  }

  auto node_layers = [&](const float* xa, const float* xb,
                         const int* bta, const int* btb, int npass, int pool_base) {
    const int nn = npass * N_NODES;
    {
      int tot = nn * 10;
      dinv_cvt_kernel<<<(tot + 255) / 256, 256, 0, stream>>>(
          cnt, dinv, xa, xb, (npass == 2) ? N_NODES : nn, xb16s, tot);
    }
    const int R = (nn + 63) / 64, RR = (R + 7) >> 3;
    dim3 fgrid(8 * RR, 1, 1);
    // layer 1: fused agg+GEMM 78->78 (Kpad 96), out ab16 ld80 (prescaled bf16)
    gemm_fused<8><<<fgrid, 256, 0, stream>>>(xb16s, cnt, col_idx, dinv, wc1t, 96,
                                             ab16, 80, bc1, nn, 78, 80);
    // layer 2: fused agg+GEMM 78->156, out xb16w ld160 (prescaled bf16)
    gemm_fused<12><<<fgrid, 256, 0, stream>>>(ab16, cnt, col_idx, dinv, wc2t, 96,
                                              xb16w, 160, bc2, nn, 156, 160);
    // layer 3: fused agg+GEMM 156->312 (Kpad 160) + segment-max pool
    gemm_fused3<<<fgrid, 256, 0, stream>>>(xb16w, cnt, col_idx, dinv, wc3t, 160,
                                           (int*)pooled, 320, bc3, nn, 312,
                                           bta, btb, (npass == 2) ? N_NODES : nn,
                                           pool_base, pool_base + N_GRAPH,
                                           pool_base + npass * N_GRAPH);
  };

  if (batched) {
    const int echunks = (2 * N_EDGES + ECHUNK - 1) / ECHUNK;
    hipMemsetAsync(cnt, 0, (size_t)NNW * 4 + (size_t)512 * 320 * 4, stream);
    wa.e1 = ei1; wa.e2 = ei2; wa.cnt = cnt; wa.col = col_idx;
    wa.E = N_EDGES; wa.npass = 2; wa.rng = NNW / 8; wa.scatB = 8 * echunks;
    prep_all<<<wb + N_GRAPH + wa.scatB, 256, 0, stream>>>(wa);
    node_layers(x1, x2, bt1, bt2, 2, 0);
  } else {
    wa.e1 = ei1; wa.e2 = ei1; wa.cnt = cnt; wa.col = col_idx;
    wa.E = N_EDGES; wa.npass = 1; wa.rng = N_NODES / 8; wa.scatB = 0;
    prep_all<<<wb + N_GRAPH, 256, 0, stream>>>(wa);
    const int echunks = (N_EDGES + ECHUNK - 1) / ECHUNK;
    hipMemsetAsync(cnt, 0, (size_t)N_NODES * 4 + (size_t)512 * 320 * 4, stream);
    scatterb_kernel<<<8 * echunks, 256, 0, stream>>>(ei1, ei1, cnt, col_idx,
                                                     N_EDGES, 1, N_NODES / 8);
    node_layers(x1, x1, bt1, bt1, 1, 0);
    hipMemsetAsync(cnt, 0, (size_t)N_NODES * 4, stream);
    scatterb_kernel<<<8 * echunks, 256, 0, stream>>>(ei2, ei2, cnt, col_idx,
                                                     N_EDGES, 1, N_NODES / 8);
    node_layers(x2, x2, bt2, bt2, 1, N_GRAPH);
  }

  // MLP tail: grouped level-merged GEMMs (6 dispatches) + micro Wo
  grp2(mkjob(pooled, 320, 1, wg1t, 320, wg1o, 160, bg1, 512, 320, 156, 1, 1, 0, 160),
       mkjob(cv16,   960, 0, wr1t, 960, wr1o, 2048, br1, 256, 960, 2048, 1, 1, 0, 2048));
  grp2(mkjob(wg1o,  160, 0, wg2t,  160, catbuf, 512, bg2, 512,  160,  128, 0, 1, 256, 128),
       mkjob(wr1o, 2048, 0, wr2t, 2048, wr2o,   512, br2, 256, 2048,  512, 1, 1, 0, 512));
  grp1(mkjob(wr2o, 512, 0, wr3t, 512, catbuf + 256, 512, br3, 256, 512, 256, 1, 1, 0, 256));
  grp1(mkjob(catbuf, 512, 0, wf1t,  512, wf1o, 1024, bf1, 256,  512, 1024, 1, 1, 0, 1024));
  grp1(mkjob(wf1o,  1024, 0, wf2t, 1024, wf2o,  512, bf2, 256, 1024,  512, 1, 1, 0, 512));
  grp1(mkjob(wf2o,   512, 0, wf3t,  512, wf3o,  128, bf3, 256,  512,  128, 1, 0, 0, 128));
  wo_kernel<<<2, 256, 0, stream>>>(wf3o, Wo, bo, out);
}

// Round 9
// 371.570 us; speedup vs baseline: 1.6844x; 1.1144x over previous
//
#include <hip/hip_runtime.h>

#define N_NODES 20000
#define N_EDGES 320000
#define N_GRAPH 256
#define ECHUNK 2048
#define DCAP 64

__device__ __forceinline__ ushort f2b(float f) {  // fp32 -> bf16 RNE
  unsigned u = __float_as_uint(f);
  u += 0x7FFFu + ((u >> 16) & 1u);
  return (ushort)(u >> 16);
}
__device__ __forceinline__ float b2f(ushort u) {
  return __uint_as_float(((unsigned)u) << 16);
}

typedef __attribute__((ext_vector_type(8))) short bf16x8;
typedef __attribute__((ext_vector_type(4))) float f32x4;

// ---- bf16x8 accumulate helper (gather path) ----
__device__ __forceinline__ void acc8(float* a, uint4 u) {
  a[0] += __uint_as_float(u.x << 16);
  a[1] += __uint_as_float(u.x & 0xFFFF0000u);
  a[2] += __uint_as_float(u.y << 16);
  a[3] += __uint_as_float(u.y & 0xFFFF0000u);
  a[4] += __uint_as_float(u.z << 16);
  a[5] += __uint_as_float(u.z & 0xFFFF0000u);
  a[6] += __uint_as_float(u.w << 16);
  a[7] += __uint_as_float(u.w & 0xFFFF0000u);
}

// ---------------- FUSED agg + bf16 MFMA GEMM (layers 1 & 2) ----------------
// Gathers + sums dinv-prescaled neighbor rows of h (ld 80, 10 uint4 chunks)
// directly into the A-tile LDS (fp32 accum -> f2b), then the K=96 MFMA loop.
// Epilogue: bias + relu + dinv[row] prescale + bf16 store, zero cols [M,cwz).
// BN trimmed to cover M only (BN_T=5 -> 80 cols for M=78; 10 -> 160 for 156).
template <int BN_T>  // BN = BN_T*16
__launch_bounds__(256)
__global__ void gemm_fused(const ushort* __restrict__ h,
                           const int* __restrict__ cnt,
                           const ushort* __restrict__ col_idx,
                           const float* __restrict__ dinv,
                           const ushort* __restrict__ Bt, int ldbt,
                           ushort* __restrict__ C, int ldc,
                           const float* __restrict__ bias,
                           int Nr, int M, int cwz) {
  constexpr int BM = 64, BN = BN_T * 16, LA = 104;
  __shared__ __align__(16) ushort Afull[BM][LA];
  __shared__ __align__(16) ushort Bsl[BN][40];
  const int tid = threadIdx.x;
  const int R = (Nr + BM - 1) / BM;
  const int RR = (R + 7) >> 3;
  const int xz = blockIdx.x & 7, g = blockIdx.x >> 3;
  const int by = xz * RR + g;
  if (by >= R) return;
  const int row0 = by * BM;
  const int lane = tid & 63, w = tid >> 6;
  const uint4* hv = (const uint4*)h;

  for (int task = tid; task < BM * 10; task += 256) {
    const int r = task / 10, c = task - r * 10;
    const int n = row0 + r;
    uint4 val = make_uint4(0u, 0u, 0u, 0u);
    if (n < Nr) {
      float a[8] = {};
      acc8(a, hv[(size_t)n * 10 + c]);  // self (prescaled)
      const int beg = n << 6;
      const int end = beg + min(cnt[n], DCAP);
      int e = beg;
      for (; e + 3 < end; e += 4) {
        int s0 = col_idx[e], s1 = col_idx[e + 1];
        int s2 = col_idx[e + 2], s3 = col_idx[e + 3];
        acc8(a, hv[(size_t)s0 * 10 + c]); acc8(a, hv[(size_t)s1 * 10 + c]);
        acc8(a, hv[(size_t)s2 * 10 + c]); acc8(a, hv[(size_t)s3 * 10 + c]);
      }
      for (; e < end; ++e) acc8(a, hv[(size_t)col_idx[e] * 10 + c]);
      const float dn = dinv[n];
      ushort o[8];
#pragma unroll
      for (int j = 0; j < 8; ++j) o[j] = f2b(dn * a[j]);
      val = *(uint4*)o;
    }
    *(uint4*)&Afull[r][c * 8] = val;
  }
  for (int task = tid; task < BM * 2; task += 256) {
    const int r = task >> 1, c2 = task & 1;
    *(uint4*)&Afull[r][80 + c2 * 8] = make_uint4(0u, 0u, 0u, 0u);
  }
  __syncthreads();

  f32x4 acc[BN_T] = {};
  const int mrow = w * 16;
  const int lm = lane & 15, lq = (lane >> 4) * 8;
  for (int t = 0; t < 3; ++t) {
    const int k0 = t * 32;
    for (int s = tid; s < BN * 4; s += 256) {
      const int br = s >> 2, bo = (s & 3) * 8;
      *(uint4*)&Bsl[br][bo] = *(const uint4*)&Bt[(size_t)br * ldbt + k0 + bo];
    }
    __syncthreads();
    bf16x8 af = *(const bf16x8*)&Afull[mrow + lm][k0 + lq];
#pragma unroll
    for (int nt = 0; nt < BN_T; ++nt) {
      bf16x8 bf = *(const bf16x8*)&Bsl[nt * 16 + lm][lq];
      acc[nt] = __builtin_amdgcn_mfma_f32_16x16x32_bf16(af, bf, acc[nt], 0, 0, 0);
    }
    __syncthreads();
  }

  const int rquad = (lane >> 4) * 4;
#pragma unroll
  for (int nt = 0; nt < BN_T; ++nt) {
    const int cc = nt * 16 + lm;
    if (cc >= cwz) continue;
    const bool cval = cc < M;
    const float bv = cval ? bias[cc] : 0.f;
#pragma unroll
    for (int r = 0; r < 4; ++r) {
      const int rr = row0 + mrow + rquad + r;
      if (rr >= Nr) continue;
      float v = cval ? fmaxf(acc[nt][r] + bv, 0.f) * dinv[rr] : 0.f;
      C[(size_t)rr * ldc + cc] = f2b(v);
    }
  }
}

// ---------------- bf16 MFMA GEMM, 128x128 tile + fused segment-max pool ----------------
// (layer 3 only) pooled pre-zeroed; relu'd >=0 -> int atomicMax on float bits.
template <int POOL>
__launch_bounds__(256)
__global__ void gemm_mfma(const ushort* __restrict__ A, int lda,
                          const ushort* __restrict__ Bt, int ldbt,
                          void* __restrict__ Cv, int ldc,
                          const float* __restrict__ bias,
                          int Nr, int Kpad, int M, int do_relu, int obf,
                          const float* __restrict__ dsc, int cwz,
                          const int* __restrict__ bA, const int* __restrict__ bB,
                          int nsplit, int gA, int gB, int gTot) {
  constexpr int BM = 128, BN = 128, BK = 32, LK = 40;
  __shared__ __align__(16) ushort Asl[BM][LK];
  __shared__ __align__(16) ushort Bsl[BN][LK];
  const int tid = threadIdx.x;
  const int Cc = (M + BN - 1) / BN;
  const int R = (Nr + BM - 1) / BM;
  const int RR = (R + 7) >> 3;
  const int xz = blockIdx.x & 7, g = blockIdx.x >> 3;
  const int q = g / Cc;
  const int by = xz * RR + q, bx = g - q * Cc;
  if (by >= R) return;
  const int row0 = by * BM, col0 = bx * BN;

  const int lane = tid & 63, w = tid >> 6;
  const int a_r = tid >> 1, a_h = tid & 1;

  const int nst = Kpad / BK;

  uint4 pa0, pa1, pb0, pb1;
  auto load_tile = [&](int k0) {
    if (row0 + a_r < Nr) {
      const uint4* p = (const uint4*)(A + (size_t)(row0 + a_r) * lda + k0 + a_h * 16);
      pa0 = p[0]; pa1 = p[1];
    } else {
      pa0 = make_uint4(0u, 0u, 0u, 0u); pa1 = pa0;
    }
    const uint4* pq = (const uint4*)(Bt + (size_t)(col0 + a_r) * ldbt + k0 + a_h * 16);
    pb0 = pq[0]; pb1 = pq[1];
  };
  auto commit = [&]() {
    *(uint4*)&Asl[a_r][a_h * 16] = pa0;
    *(uint4*)&Asl[a_r][a_h * 16 + 8] = pa1;
    *(uint4*)&Bsl[a_r][a_h * 16] = pb0;
    *(uint4*)&Bsl[a_r][a_h * 16 + 8] = pb1;
  };

  f32x4 acc[2][8] = {};
  const int mrow = w * 32;
  const int lm = lane & 15, lq = (lane >> 4) * 8;

  load_tile(0);
  for (int t = 0; t < nst; ++t) {
    commit();
    __syncthreads();
    if (t + 1 < nst) load_tile((t + 1) * BK);
    bf16x8 af0 = *(const bf16x8*)&Asl[mrow + lm][lq];
    bf16x8 af1 = *(const bf16x8*)&Asl[mrow + 16 + lm][lq];
#pragma unroll
    for (int nt = 0; nt < 8; ++nt) {
      bf16x8 bf = *(const bf16x8*)&Bsl[nt * 16 + lm][lq];
      acc[0][nt] = __builtin_amdgcn_mfma_f32_16x16x32_bf16(af0, bf, acc[0][nt], 0, 0, 0);
      acc[1][nt] = __builtin_amdgcn_mfma_f32_16x16x32_bf16(af1, bf, acc[1][nt], 0, 0, 0);
    }
    __syncthreads();
  }

  const int rquad = (lane >> 4) * 4;

  if constexpr (POOL) {
    __shared__ int Ps[4][BN];
    for (int idx = tid; idx < 4 * BN; idx += 256) Ps[idx >> 7][idx & 127] = 0;
    __syncthreads();
    const int g0 = (row0 < nsplit) ? gA + bA[row0] : gB + bB[row0 - nsplit];
    int gr8[2][4];
#pragma unroll
    for (int mt = 0; mt < 2; ++mt)
#pragma unroll
      for (int r = 0; r < 4; ++r) {
        const int rr = row0 + mrow + mt * 16 + rquad + r;
        gr8[mt][r] = (rr < Nr)
                         ? ((rr < nsplit) ? gA + bA[rr] : gB + bB[rr - nsplit])
                         : -1;
      }
#pragma unroll
    for (int mt = 0; mt < 2; ++mt)
#pragma unroll
      for (int nt = 0; nt < 8; ++nt) {
        const int cl = nt * 16 + lm;
        if (col0 + cl >= M) continue;
        const float bv = bias[col0 + cl];
#pragma unroll
        for (int r = 0; r < 4; ++r) {
          const int gg = gr8[mt][r];
          if (gg < 0) continue;
          const float v = fmaxf(acc[mt][nt][r] + bv, 0.f);
          atomicMax(&Ps[gg - g0][cl], __float_as_int(v));
        }
      }
    __syncthreads();
    for (int idx = tid; idx < 4 * BN; idx += 256) {
      const int s = idx >> 7, c = idx & 127;
      const int gg = g0 + s, cc = col0 + c;
      if (gg < gTot && cc < M)
        atomicMax((int*)Cv + (size_t)gg * ldc + cc, Ps[s][c]);
    }
    return;
  }

  const int cz = (cwz > M) ? cwz : M;
#pragma unroll
  for (int mt = 0; mt < 2; ++mt) {
#pragma unroll
    for (int nt = 0; nt < 8; ++nt) {
      const int cc = col0 + nt * 16 + lm;
      if (cc >= cz) continue;
      const bool cval = cc < M;
      const float bv = (cval && bias) ? bias[cc] : 0.f;
#pragma unroll
      for (int r = 0; r < 4; ++r) {
        const int rr = row0 + mrow + mt * 16 + rquad + r;
        if (rr >= Nr) continue;
        float v = cval ? (acc[mt][nt][r] + bv) : 0.f;
        if (do_relu) v = fmaxf(v, 0.f);
        if (dsc) v *= dsc[rr];
        if (obf) ((ushort*)Cv)[(size_t)rr * ldc + cc] = f2b(v);
        else     ((float*)Cv)[(size_t)rr * ldc + cc] = v;
      }
    }
  }
}

// ---------------- grouped small-GEMM: 32x64 tile, 4 waves split K in-block ----------------
struct GJob {
  const void* A; const ushort* Bt; void* C; const float* bias;
  int lda, a_f32, ldbt, ldc, Nr, Kpad, M, relu, obf, rsplit, cpad, rb, cb, blk0;
};

__launch_bounds__(256)
__global__ void gemm_grp(GJob j0, GJob j1, int njobs) {
  GJob j = (njobs > 1 && (int)blockIdx.x >= j1.blk0) ? j1 : j0;
  const int local = blockIdx.x - j.blk0;
  const int by = local / j.cb, bx = local - by * j.cb;
  const int row0 = by * 32, col0 = bx * 64;
  const int tid = threadIdx.x, lane = tid & 63, w = tid >> 6;

  __shared__ __align__(16) char smem[32768];
  ushort (*Asl)[32][40] = (ushort (*)[32][40])smem;           // 10240 B
  ushort (*Bsl)[64][40] = (ushort (*)[64][40])(smem + 10240); // 20480 B
  float  (*Rs)[32][64]  = (float  (*)[32][64])smem;           // 32768 B (aliased)

  const int a_r = lane >> 1, a_h = lane & 1;
  const int lm = lane & 15, lq = (lane >> 4) * 8;
  const int nst = j.Kpad / 32;

  uint4 ra[4], rb[4];
  auto gload = [&](int t) {
    const int k0 = t * 32;
    const int ar = row0 + a_r;
    if (j.a_f32) {
      if (ar < j.Nr) {
        const uint4* p = (const uint4*)((const float*)j.A + (size_t)ar * j.lda + k0 + a_h * 16);
        ra[0] = p[0]; ra[1] = p[1]; ra[2] = p[2]; ra[3] = p[3];
      } else {
        ra[0] = make_uint4(0u, 0u, 0u, 0u); ra[1] = ra[0]; ra[2] = ra[0]; ra[3] = ra[0];
      }
    } else {
      if (ar < j.Nr) {
        const uint4* p = (const uint4*)((const ushort*)j.A + (size_t)ar * j.lda + k0 + a_h * 16);
        ra[0] = p[0]; ra[1] = p[1];
      } else {
        ra[0] = make_uint4(0u, 0u, 0u, 0u); ra[1] = ra[0];
      }
    }
    const uint4* q = (const uint4*)(j.Bt + (size_t)(col0 + lane) * j.ldbt + k0);
    rb[0] = q[0]; rb[1] = q[1]; rb[2] = q[2]; rb[3] = q[3];
  };
  auto commit = [&]() {
    if (j.a_f32) {
      ushort tmp[16];
      const float* f = (const float*)&ra[0];
#pragma unroll
      for (int q2 = 0; q2 < 16; ++q2) tmp[q2] = f2b(f[q2]);
      *(uint4*)&Asl[w][a_r][a_h * 16]     = *(uint4*)&tmp[0];
      *(uint4*)&Asl[w][a_r][a_h * 16 + 8] = *(uint4*)&tmp[8];
    } else {
      *(uint4*)&Asl[w][a_r][a_h * 16]     = ra[0];
      *(uint4*)&Asl[w][a_r][a_h * 16 + 8] = ra[1];
    }
    *(uint4*)&Bsl[w][lane][0]  = rb[0];
    *(uint4*)&Bsl[w][lane][8]  = rb[1];
    *(uint4*)&Bsl[w][lane][16] = rb[2];
    *(uint4*)&Bsl[w][lane][24] = rb[3];
  };

  f32x4 acc[2][4] = {};
  if (w < nst) {
    gload(w);
    for (int t = w; t < nst; t += 4) {
      commit();
      bf16x8 af0 = *(const bf16x8*)&Asl[w][lm][lq];
      bf16x8 af1 = *(const bf16x8*)&Asl[w][16 + lm][lq];
      bf16x8 bq0 = *(const bf16x8*)&Bsl[w][lm][lq];
      bf16x8 bq1 = *(const bf16x8*)&Bsl[w][16 + lm][lq];
      bf16x8 bq2 = *(const bf16x8*)&Bsl[w][32 + lm][lq];
      bf16x8 bq3 = *(const bf16x8*)&Bsl[w][48 + lm][lq];
      if (t + 4 < nst) gload(t + 4);
      acc[0][0] = __builtin_amdgcn_mfma_f32_16x16x32_bf16(af0, bq0, acc[0][0], 0, 0, 0);
      acc[0][1] = __builtin_amdgcn_mfma_f32_16x16x32_bf16(af0, bq1, acc[0][1], 0, 0, 0);
      acc[0][2] = __builtin_amdgcn_mfma_f32_16x16x32_bf16(af0, bq2, acc[0][2], 0, 0, 0);
      acc[0][3] = __builtin_amdgcn_mfma_f32_16x16x32_bf16(af0, bq3, acc[0][3], 0, 0, 0);
      acc[1][0] = __builtin_amdgcn_mfma_f32_16x16x32_bf16(af1, bq0, acc[1][0], 0, 0, 0);
      acc[1][1] = __builtin_amdgcn_mfma_f32_16x16x32_bf16(af1, bq1, acc[1][1], 0, 0, 0);
      acc[1][2] = __builtin_amdgcn_mfma_f32_16x16x32_bf16(af1, bq2, acc[1][2], 0, 0, 0);
      acc[1][3] = __builtin_amdgcn_mfma_f32_16x16x32_bf16(af1, bq3, acc[1][3], 0, 0, 0);
    }
  }

  __syncthreads();  // all waves done with staging LDS; safe to alias as Rs
  const int rquad = (lane >> 4) * 4;
#pragma unroll
  for (int mt = 0; mt < 2; ++mt)
#pragma unroll
    for (int nt = 0; nt < 4; ++nt)
#pragma unroll
      for (int r = 0; r < 4; ++r)
        Rs[w][mt * 16 + rquad + r][nt * 16 + lm] = acc[mt][nt][r];
  __syncthreads();

  const int rrow = tid >> 3, cs = (tid & 7) * 8;
  float v[8];
  {
    float4 x0 = *(const float4*)&Rs[0][rrow][cs];
    float4 x1 = *(const float4*)&Rs[0][rrow][cs + 4];
    v[0] = x0.x; v[1] = x0.y; v[2] = x0.z; v[3] = x0.w;
    v[4] = x1.x; v[5] = x1.y; v[6] = x1.z; v[7] = x1.w;
  }
#pragma unroll
  for (int ww = 1; ww < 4; ++ww) {
    float4 x0 = *(const float4*)&Rs[ww][rrow][cs];
    float4 x1 = *(const float4*)&Rs[ww][rrow][cs + 4];
    v[0] += x0.x; v[1] += x0.y; v[2] += x0.z; v[3] += x0.w;
    v[4] += x1.x; v[5] += x1.y; v[6] += x1.z; v[7] += x1.w;
  }
  const int rg = row0 + rrow;
  if (rg < j.Nr) {
    int rm = rg, rq = 0;
    if (j.rsplit) { rq = rg / j.rsplit; rm = rg - rq * j.rsplit; }
#pragma unroll
    for (int q = 0; q < 8; ++q) {
      const int cc = col0 + cs + q;
      if (cc >= j.cpad) break;
      float x = 0.f;
      if (cc < j.M) {
        x = v[q] + j.bias[cc];
        if (j.relu) x = fmaxf(x, 0.f);
      }
      const size_t di = (size_t)rm * j.ldc + (size_t)rq * j.M + cc;
      if (j.obf) ((ushort*)j.C)[di] = f2b(x);
      else       ((float*)j.C)[di] = x;
    }
  }
}

// ---- final Wo layer: out[256][2] = wf3o[256][128] @ Wo[128][2] + bo ----
__global__ void wo_kernel(const float* __restrict__ wf3o, const float* __restrict__ Wo,
                          const float* __restrict__ bo, float* __restrict__ out) {
  int gid = blockIdx.x * blockDim.x + threadIdx.x;
  if (gid >= N_GRAPH * 2) return;
  int row = gid >> 1, col = gid & 1;
  float v = bo[col];
  const float* a = wf3o + (size_t)row * 128;
  for (int k = 0; k < 128; ++k) v += a[k] * Wo[k * 2 + col];
  out[gid] = v;
}

// ---------------- one-shot prep: weight transposes + rownorm + edge scatter ----------------
struct WJob { const float* W; ushort* T; int Mv, Kv, Mp, Kp, blk0; };
struct WArgs {
  WJob j[11]; int wblocks; const float* cell; ushort* cv;
  const int* e1; const int* e2; int* cnt; ushort* col; int E, npass, rng, scatB;
};

__launch_bounds__(256)
__global__ void prep_all(WArgs a) {
  const int bid = blockIdx.x, tid = threadIdx.x;
  if (bid < a.wblocks) {
    __shared__ float t[32][33];
    int ji = 0;
#pragma unroll
    for (int i = 1; i < 11; ++i)
      if (bid >= a.j[i].blk0) ji = i;
    WJob wj = a.j[ji];
    const int lt = bid - wj.blk0;
    const int ktiles = wj.Kp >> 5;
    const int tn = lt / ktiles, tk = lt - tn * ktiles;
    const int n0 = tn << 5, k0 = tk << 5;
    const int c = tid & 31, r = tid >> 5;
    const int nn = n0 + c;
#pragma unroll
    for (int i = 0; i < 4; ++i) {
      const int k = k0 + r + i * 8;
      t[r + i * 8][c] = (k < wj.Kv && nn < wj.Mv) ? wj.W[(size_t)k * wj.Mv + nn] : 0.f;
    }
    __syncthreads();
    const int k = k0 + c;
#pragma unroll
    for (int i = 0; i < 4; ++i) {
      const int n = n0 + r + i * 8;
      wj.T[(size_t)n * wj.Kp + k] = f2b(t[c][r + i * 8]);
    }
    return;
  }
  if (bid < a.wblocks + N_GRAPH) {
    __shared__ float red[256];
    const int g = bid - a.wblocks;
    const float* row = a.cell + (size_t)g * 954;
    float s = 0.f;
    for (int f = tid; f < 954; f += 256) { float vv = row[f]; s += vv * vv; }
    red[tid] = s;
    __syncthreads();
    for (int off2 = 128; off2 > 0; off2 >>= 1) {
      if (tid < off2) red[tid] += red[tid + off2];
      __syncthreads();
    }
    const float inv = 1.f / fmaxf(sqrtf(red[0]), 1e-12f);
    ushort* orow = a.cv + (size_t)g * 960;
    for (int f = tid; f < 954; f += 256) orow[f] = f2b(row[f] * inv);
    for (int f = 954 + tid; f < 960; f += 256) orow[f] = 0;
    return;
  }
  // bucketed edge scatter (batched path; cnt pre-zeroed)
  const int sb = bid - a.wblocks - N_GRAPH;
  const int xcd = sb & 7;
  const int lo = xcd * a.rng, hi = lo + a.rng;
  const int base = (sb >> 3) * ECHUNK;
  const int TE = a.npass * a.E;
  for (int i = tid; i < ECHUNK; i += 256) {
    int e = base + i;
    if (e >= TE) break;
    int d, s;
    if (e < a.E) { d = a.e1[a.E + e]; s = a.e1[e]; }
    else { int jj = e - a.E; d = N_NODES + a.e2[a.E + jj]; s = N_NODES + a.e2[jj]; }
    if (d >= lo && d < hi) {
      int p = atomicAdd(&a.cnt[d], 1);
      if (p < DCAP) a.col[((size_t)d << 6) + p] = (ushort)s;
    }
  }
}

// standalone scatter (non-batched second pass)
__global__ void scatterb_kernel(const int* __restrict__ e1, const int* __restrict__ e2,
                                int* __restrict__ cnt, ushort* __restrict__ col_idx,
                                int E, int npass, int rng) {
  const int xcd = blockIdx.x & 7;
  const int lo = xcd * rng, hi = lo + rng;
  const int base = (blockIdx.x >> 3) * ECHUNK;
  const int TE = npass * E;
  for (int i = threadIdx.x; i < ECHUNK; i += 256) {
    int e = base + i;
    if (e >= TE) break;
    int d, s;
    if (e < E) { d = e1[E + e]; s = e1[e]; }
    else { int jj = e - E; d = N_NODES + e2[E + jj]; s = N_NODES + e2[jj]; }
    if (d >= lo && d < hi) {
      int p = atomicAdd(&cnt[d], 1);
      if (p < DCAP) col_idx[((size_t)d << 6) + p] = (ushort)s;
    }
  }
}

// dinv = rsqrt(deg+1), x -> bf16 prescaled by dinv (ld 80, pads zeroed)
__global__ void dinv_cvt_kernel(const int* __restrict__ cnt, float* __restrict__ dinv,
                                const float* __restrict__ xa, const float* __restrict__ xb,
                                int nsplit, ushort* __restrict__ dst, int total) {
  int gid = blockIdx.x * blockDim.x + threadIdx.x;
  if (gid >= total) return;
  int n = gid / 10, v = gid - n * 10;
  const float sc = rsqrtf((float)(cnt[n] + 1));
  if (v == 0) dinv[n] = sc;
  const float* src = (n < nsplit) ? xa + (size_t)n * 78 : xb + (size_t)(n - nsplit) * 78;
  const int f0 = v * 8;
  ushort o[8];
#pragma unroll
  for (int jj = 0; jj < 8; ++jj)
    o[jj] = (f0 + jj < 78) ? f2b(src[f0 + jj] * sc) : 0;
  ((uint4*)(dst + (size_t)n * 80))[v] = *(uint4*)o;
}

// ---- layer-3 aggregation (separate; feeds the pool GEMM) ----
__global__ void aggb_flat(const ushort* __restrict__ h, const int* __restrict__ cnt,
                          const ushort* __restrict__ col_idx, const float* __restrict__ dinv,
                          ushort* __restrict__ out, int in_ld, int out_ld,
                          int V, int total) {
  int gid = blockIdx.x * blockDim.x + threadIdx.x;
  if (gid >= total) return;
  int n = gid / V, v = gid - n * V;
  const uint4* hv = (const uint4*)h;
  const int ivs = in_ld >> 3;
  float a[8] = {};
  acc8(a, hv[(size_t)n * ivs + v]);  // self (prescaled)
  const int beg = n << 6;
  const int end = beg + min(cnt[n], DCAP);
  int e = beg;
  for (; e + 3 < end; e += 4) {
    int s0 = col_idx[e], s1 = col_idx[e + 1], s2 = col_idx[e + 2], s3 = col_idx[e + 3];
    uint4 u0 = hv[(size_t)s0 * ivs + v], u1 = hv[(size_t)s1 * ivs + v];
    uint4 u2 = hv[(size_t)s2 * ivs + v], u3 = hv[(size_t)s3 * ivs + v];
    acc8(a, u0); acc8(a, u1); acc8(a, u2); acc8(a, u3);
  }
  for (; e < end; ++e)
    acc8(a, hv[(size_t)col_idx[e] * ivs + v]);
  const float din = dinv[n];
  ushort o[8];
#pragma unroll
  for (int jj = 0; jj < 8; ++jj) o[jj] = f2b(din * a[jj]);
  ((uint4*)(out + (size_t)n * out_ld))[v] = *(uint4*)o;
}

// ------------------------- launcher -------------------------
extern "C" void kernel_launch(void* const* d_in, const int* in_sizes, int n_in,
                              void* d_out, int out_size, void* d_ws, size_t ws_size,
                              hipStream_t stream) {
  (void)in_sizes; (void)n_in; (void)out_size;
  const float* x1  = (const float*)d_in[0];
  const int*   ei1 = (const int*)d_in[1];
  const int*   bt1 = (const int*)d_in[2];
  const float* x2  = (const float*)d_in[3];
  const int*   ei2 = (const int*)d_in[4];
  const int*   bt2 = (const int*)d_in[5];
  const float* cell = (const float*)d_in[6];
  const float* Wc1 = (const float*)d_in[7];  const float* bc1 = (const float*)d_in[8];
  const float* Wc2 = (const float*)d_in[9];  const float* bc2 = (const float*)d_in[10];
  const float* Wc3 = (const float*)d_in[11]; const float* bc3 = (const float*)d_in[12];
  const float* Wg1 = (const float*)d_in[13]; const float* bg1 = (const float*)d_in[14];
  const float* Wg2 = (const float*)d_in[15]; const float* bg2 = (const float*)d_in[16];
  const float* Wr1 = (const float*)d_in[17]; const float* br1 = (const float*)d_in[18];
  const float* Wr2 = (const float*)d_in[19]; const float* br2 = (const float*)d_in[20];
  const float* Wr3 = (const float*)d_in[21]; const float* br3 = (const float*)d_in[22];
  const float* Wf1 = (const float*)d_in[23]; const float* bf1 = (const float*)d_in[24];
  const float* Wf2 = (const float*)d_in[25]; const float* bf2 = (const float*)d_in[26];
  const float* Wf3 = (const float*)d_in[27]; const float* bf3 = (const float*)d_in[28];
  const float* Wo  = (const float*)d_in[29]; const float* bo  = (const float*)d_in[30];
  float* out = (float*)d_out;

  const bool batched = ws_size >= (size_t)95 * 1024 * 1024;
  const int NPASS = batched ? 2 : 1;
  const int NNW = NPASS * N_NODES;

  char* ws = (char*)d_ws;
  size_t off = 0;
  auto alloc_f = [&](size_t ne) {
    ne = (ne + 3) & ~(size_t)3;
    float* p = (float*)(ws + off); off += ne * 4; return p;
  };
  auto alloc_i = [&](size_t ne) {
    ne = (ne + 3) & ~(size_t)3;
    int* p = (int*)(ws + off); off += ne * 4; return p;
  };
  ushort* xb16w = (ushort*)alloc_f((size_t)NNW * 80);  // bf16 prescaled h, ld 160 (L2 out)
  ushort* ab16  = (ushort*)alloc_f((size_t)NNW * 80);  // L1 out (ld80) / L3 agg out (ld160)
  ushort* xb16s = (ushort*)alloc_f((size_t)NNW * 40);  // bf16 prescaled x, ld 80
  float* dinv   = alloc_f(NNW);
  int* cnt      = alloc_i(NNW);                         // cnt+pooled contiguous: 1 memset
  float* pooled = alloc_f((size_t)512 * 320);           // fp32 (atomicMax int-bits), ld 320
  ushort* cv16  = (ushort*)alloc_f((size_t)N_GRAPH * 480);   // bf16 cell, ld 960
  ushort* wg1o  = (ushort*)alloc_f((size_t)512 * 80);        // bf16, ld 160
  ushort* wr1o  = (ushort*)alloc_f((size_t)256 * 1024);      // bf16, ld 2048
  ushort* wr2o  = (ushort*)alloc_f((size_t)256 * 256);       // bf16, ld 512
  ushort* catbuf = (ushort*)alloc_f((size_t)256 * 256);      // bf16, ld 512
  ushort* wf1o  = (ushort*)alloc_f((size_t)256 * 512);       // bf16, ld 1024
  ushort* wf2o  = (ushort*)alloc_f((size_t)256 * 256);       // bf16, ld 512
  float* wf3o   = alloc_f((size_t)256 * 128);                // fp32, ld 128
  ushort* wc1t  = (ushort*)alloc_f(128 * 96 / 2);
  ushort* wc2t  = (ushort*)alloc_f(192 * 96 / 2);
  ushort* wc3t  = (ushort*)alloc_f(384 * 160 / 2);
  ushort* wr1t  = (ushort*)alloc_f(2048 * 960 / 2);
  ushort* wr2t  = (ushort*)alloc_f(512 * 2048 / 2);
  ushort* wf1t  = (ushort*)alloc_f(1024 * 512 / 2);
  ushort* wg1t  = (ushort*)alloc_f(192 * 320 / 2);
  ushort* wg2t  = (ushort*)alloc_f(128 * 160 / 2);
  ushort* wr3t  = (ushort*)alloc_f(256 * 512 / 2);
  ushort* wf2t  = (ushort*)alloc_f(512 * 1024 / 2);
  ushort* wf3t  = (ushort*)alloc_f(128 * 512 / 2);
  ushort* col_idx = (ushort*)alloc_i((size_t)NNW * DCAP / 2);

  auto mkjob = [&](const void* A, int lda, int a_f32, const ushort* Bt, int ldbt,
                   void* C, int ldc, const float* bias, int Nr, int Kpad, int M,
                   int relu, int obf, int rsplit, int cpad) {
    GJob g; g.A = A; g.Bt = Bt; g.C = C; g.bias = bias;
    g.lda = lda; g.a_f32 = a_f32; g.ldbt = ldbt; g.ldc = ldc;
    g.Nr = Nr; g.Kpad = Kpad; g.M = M; g.relu = relu; g.obf = obf;
    g.rsplit = rsplit; g.cpad = cpad;
    g.rb = (Nr + 31) / 32; g.cb = (M + 63) / 64; g.blk0 = 0;
    return g;
  };
  auto grp1 = [&](GJob a) {
    gemm_grp<<<a.rb * a.cb, 256, 0, stream>>>(a, a, 1);
  };
  auto grp2 = [&](GJob a, GJob b) {
    b.blk0 = a.rb * a.cb;
    gemm_grp<<<b.blk0 + b.rb * b.cb, 256, 0, stream>>>(a, b, 2);
  };
  auto mfma_pool = [&](const ushort* A, int lda, const ushort* Bt, int ldbt,
                       const float* bias, int Nr, int Kpad, int M,
                       const int* bA, const int* bB, int nsplit, int gA, int gB, int gTot) {
    int Cc = (M + 127) / 128, R = (Nr + 127) / 128, RR = (R + 7) >> 3;
    dim3 grid(8 * RR * Cc, 1, 1);
    gemm_mfma<1><<<grid, 256, 0, stream>>>(A, lda, Bt, ldbt, pooled, 320, bias,
                                           Nr, Kpad, M, 1, 0, nullptr, 0,
                                           bA, bB, nsplit, gA, gB, gTot);
  };

  // prep args: 11 weight transposes + rownorm (+ batched scatter)
  WArgs wa{};
  int wb = 0;
  {
    int nj = 0;
    auto addw = [&](const float* W, ushort* T, int Mv, int Kv, int Mp, int Kp) {
      wa.j[nj].W = W; wa.j[nj].T = T; wa.j[nj].Mv = Mv; wa.j[nj].Kv = Kv;
      wa.j[nj].Mp = Mp; wa.j[nj].Kp = Kp; wa.j[nj].blk0 = wb;
      wb += (Mp >> 5) * (Kp >> 5); ++nj;
    };
    addw(Wc1, wc1t,   78,   78,  128,   96);
    addw(Wc2, wc2t,  156,   78,  192,   96);
    addw(Wc3, wc3t,  312,  156,  384,  160);
    addw(Wr1, wr1t, 2048,  954, 2048,  960);
    addw(Wr2, wr2t,  512, 2048,  512, 2048);
    addw(Wf1, wf1t, 1024,  512, 1024,  512);
    addw(Wg1, wg1t,  156,  312,  192,  320);
    addw(Wg2, wg2t,  128,  156,  128,  160);
    addw(Wr3, wr3t,  256,  512,  256,  512);
    addw(Wf2, wf2t,  512, 1024,  512, 1024);
    addw(Wf3, wf3t,  128,  512,  128,  512);
    wa.wblocks = wb; wa.cell = cell; wa.cv = cv16;
  }

  auto node_layers = [&](const float* xa, const float* xb,
                         const int* bta, const int* btb, int npass, int pool_base) {
    const int nn = npass * N_NODES;
    {
      int tot = nn * 10;
      dinv_cvt_kernel<<<(tot + 255) / 256, 256, 0, stream>>>(
          cnt, dinv, xa, xb, (npass == 2) ? N_NODES : nn, xb16s, tot);
    }
    const int R = (nn + 63) / 64, RR = (R + 7) >> 3;
    dim3 fgrid(8 * RR, 1, 1);
    // layer 1: fused agg+GEMM 78->78 (Kpad 96, BN=80), out ab16 ld80
    gemm_fused<5><<<fgrid, 256, 0, stream>>>(xb16s, cnt, col_idx, dinv, wc1t, 96,
                                             ab16, 80, bc1, nn, 78, 80);
    // layer 2: fused agg+GEMM 78->156 (BN=160), out xb16w ld160
    gemm_fused<10><<<fgrid, 256, 0, stream>>>(ab16, cnt, col_idx, dinv, wc2t, 96,
                                              xb16w, 160, bc2, nn, 156, 160);
    // layer 3: agg (ld160) -> ab16 ld160 -> MFMA 156->312 + fused max-pool
    {
      int tot = nn * 20;
      aggb_flat<<<(tot + 255) / 256, 256, 0, stream>>>(xb16w, cnt, col_idx, dinv,
                                                       ab16, 160, 160, 20, tot);
    }
    mfma_pool(ab16, 160, wc3t, 160, bc3, nn, 160, 312,
              bta, btb, (npass == 2) ? N_NODES : nn,
              pool_base, pool_base + N_GRAPH, pool_base + npass * N_GRAPH);
  };

  if (batched) {
    const int echunks = (2 * N_EDGES + ECHUNK - 1) / ECHUNK;
    hipMemsetAsync(cnt, 0, (size_t)NNW * 4 + (size_t)512 * 320 * 4, stream);
    wa.e1 = ei1; wa.e2 = ei2; wa.cnt = cnt; wa.col = col_idx;
    wa.E = N_EDGES; wa.npass = 2; wa.rng = NNW / 8; wa.scatB = 8 * echunks;
    prep_all<<<wb + N_GRAPH + wa.scatB, 256, 0, stream>>>(wa);
    node_layers(x1, x2, bt1, bt2, 2, 0);
  } else {
    wa.e1 = ei1; wa.e2 = ei1; wa.cnt = cnt; wa.col = col_idx;
    wa.E = N_EDGES; wa.npass = 1; wa.rng = N_NODES / 8; wa.scatB = 0;
    prep_all<<<wb + N_GRAPH, 256, 0, stream>>>(wa);
    const int echunks = (N_EDGES + ECHUNK - 1) / ECHUNK;
    hipMemsetAsync(cnt, 0, (size_t)N_NODES * 4 + (size_t)512 * 320 * 4, stream);
    scatterb_kernel<<<8 * echunks, 256, 0, stream>>>(ei1, ei1, cnt, col_idx,
                                                     N_EDGES, 1, N_NODES / 8);
    node_layers(x1, x1, bt1, bt1, 1, 0);
    hipMemsetAsync(cnt, 0, (size_t)N_NODES * 4, stream);
    scatterb_kernel<<<8 * echunks, 256, 0, stream>>>(ei2, ei2, cnt, col_idx,
                                                     N_EDGES, 1, N_NODES / 8);
    node_layers(x2, x2, bt2, bt2, 1, N_GRAPH);
  }

  // MLP tail: grouped level-merged GEMMs (6 dispatches) + micro Wo
  grp2(mkjob(pooled, 320, 1, wg1t, 320, wg1o, 160, bg1, 512, 320, 156, 1, 1, 0, 160),
       mkjob(cv16,   960, 0, wr1t, 960, wr1o, 2048, br1, 256, 960, 2048, 1, 1, 0, 2048));
  grp2(mkjob(wg1o,  160, 0, wg2t,  160, catbuf, 512, bg2, 512,  160,  128, 0, 1, 256, 128),
       mkjob(wr1o, 2048, 0, wr2t, 2048, wr2o,   512, br2, 256, 2048,  512, 1, 1, 0, 512));
  grp1(mkjob(wr2o, 512, 0, wr3t, 512, catbuf + 256, 512, br3, 256, 512, 256, 1, 1, 0, 256));
  grp1(mkjob(catbuf, 512, 0, wf1t,  512, wf1o, 1024, bf1, 256,  512, 1024, 1, 1, 0, 1024));
  grp1(mkjob(wf1o,  1024, 0, wf2t, 1024, wf2o,  512, bf2, 256, 1024,  512, 1, 1, 0, 512));
  grp1(mkjob(wf2o,   512, 0, wf3t,  512, wf3o,  128, bf3, 256,  512,  128, 1, 0, 0, 128));
  wo_kernel<<<2, 256, 0, stream>>>(wf3o, Wo, bo, out);
}